// Round 7
// baseline (505.771 us; speedup 1.0000x reference)
//
#include <hip/hip_runtime.h>
#include <hip/hip_bf16.h>

typedef unsigned short u16;
typedef __attribute__((ext_vector_type(4))) float f4;
typedef __attribute__((ext_vector_type(8))) short s16x8;
typedef __attribute__((ext_vector_type(8))) unsigned short u16x8;

__device__ __forceinline__ u16 f2bf(float x){
  unsigned u = __float_as_uint(x);
  u += 0x7fffu + ((u >> 16) & 1u);
  return (u16)(u >> 16);
}
__device__ __forceinline__ float bf2f(u16 h){ return __uint_as_float(((unsigned)h) << 16); }

__device__ __forceinline__ void gload_lds16(const u16* g, u16* l){
  __builtin_amdgcn_global_load_lds((__attribute__((address_space(1))) void*)g,
                                   (__attribute__((address_space(3))) void*)l, 16, 0, 0);
}

// ---------------- GEMM ----------------
// C[M,N] = A1[M,K1] @ B1t[N,K1]^T + A2[M,K2] @ B2t[N,K2]^T, bf16 in, fp32 acc.
struct GemmP {
  const u16* A; const u16* B;
  const u16* A2; const u16* B2;
  int K1, K2, lda, ldb, H;
  long long sAb, sAh, sBb, sBh;
  u16* C; long long sCb, sCh; int ldc;
  u16* C2;
  const float* bias; const float* bias2;
  u16* S;
};

enum { EPI_BF16=0, EPI_QUV=1, EPI_SIG=2, EPI_TANH=3, EPI_GELU=4, EPI_BD=5 };

// DB=1: 2-phase stage-early double-buffered pipeline (for small-grid / 1-2 blk/CU GEMMs)
template<int BM, int BN, int EPI, int DB>
__launch_bounds__(256)
__global__ void gemm_k(GemmP p) {
  constexpr int WN = (BN >= 128) ? 2 : 1;
  constexpr int WM = 4 / WN;
  constexpr int TM = BM / WM, TN = BN / WN;
  constexpr int FM = TM / 16, FN = TN / 16;
  constexpr int BUFE = (BM + BN) * 64;

  __shared__ __align__(16) u16 lds[BUFE * (DB ? 2 : 1)];

  const int tid = threadIdx.x;
  const int w = tid >> 6, lane = tid & 63;
  const int bz = blockIdx.z;
  const int b = bz / p.H, h = bz - b * p.H;
  const int m0 = blockIdx.x * BM, n0 = blockIdx.y * BN;

  const u16* Ab0 = p.A + (long long)b * p.sAb + (long long)h * p.sAh + (long long)m0 * p.lda;
  const u16* Bb0 = p.B + (long long)b * p.sBb + (long long)h * p.sBh + (long long)n0 * p.ldb;
  const u16* Ab1 = p.A2 ? p.A2 + (long long)m0 * p.lda : (const u16*)0;
  const u16* Bb1 = p.B2 ? p.B2 + (long long)n0 * p.ldb : (const u16*)0;

  f4 acc[FM][FN];
  #pragma unroll
  for (int i = 0; i < FM; ++i)
    #pragma unroll
    for (int j = 0; j < FN; ++j) acc[i][j] = f4{0.f, 0.f, 0.f, 0.f};

  const int s1 = p.K1 >> 6;
  const int st = s1 + (p.K2 >> 6);
  const int wM = w / WN, wN = w - wM * WN;

  auto stage = [&](int s, u16* lA_, u16* lB_) {
    const u16* Ab; const u16* Bb; int k0;
    if (s < s1) { Ab = Ab0; Bb = Bb0; k0 = s << 6; }
    else        { Ab = Ab1; Bb = Bb1; k0 = (s - s1) << 6; }
    #pragma unroll
    for (int i = 0; i < (BM >> 5); ++i) {
      int c = i * 256 + tid, row = c >> 3, cc = c & 7, sc = cc ^ (row & 7);
      gload_lds16(Ab + (long long)row * p.lda + k0 + sc * 8, lA_ + (size_t)(i * 4 + w) * 512);
    }
    #pragma unroll
    for (int i = 0; i < (BN >> 5); ++i) {
      int c = i * 256 + tid, row = c >> 3, cc = c & 7, sc = cc ^ (row & 7);
      gload_lds16(Bb + (long long)row * p.ldb + k0 + sc * 8, lB_ + (size_t)(i * 4 + w) * 512);
    }
  };

  auto compute = [&](const u16* lA_, const u16* lB_) {
    #pragma unroll
    for (int kk = 0; kk < 2; ++kk) {
      const int kb = lane >> 4;
      const int gc = kk * 4 + kb;
      s16x8 av[FM], bv[FN];
      #pragma unroll
      for (int fm = 0; fm < FM; ++fm) {
        int r = wM * TM + fm * 16 + (lane & 15);
        av[fm] = *(const s16x8*)(lA_ + r * 64 + ((gc ^ (r & 7)) << 3));
      }
      #pragma unroll
      for (int fn = 0; fn < FN; ++fn) {
        int r = wN * TN + fn * 16 + (lane & 15);
        bv[fn] = *(const s16x8*)(lB_ + r * 64 + ((gc ^ (r & 7)) << 3));
      }
      #pragma unroll
      for (int fm = 0; fm < FM; ++fm)
        #pragma unroll
        for (int fn = 0; fn < FN; ++fn)
          acc[fm][fn] = __builtin_amdgcn_mfma_f32_16x16x32_bf16(av[fm], bv[fn], acc[fm][fn], 0, 0, 0);
    }
  };

  if constexpr (DB) {
    stage(0, lds, lds + BM * 64);
    __syncthreads();
    for (int s = 0; s < st; ++s) {
      u16* cur = lds + (size_t)(s & 1) * BUFE;
      if (s + 1 < st) {
        u16* nxt = lds + (size_t)((s + 1) & 1) * BUFE;
        stage(s + 1, nxt, nxt + BM * 64);
      }
      compute(cur, cur + BM * 64);
      __syncthreads();   // drains staged loads (issued before compute) + read-safety
    }
  } else {
    for (int s = 0; s < st; ++s) {
      stage(s, lds, lds + BM * 64);
      __syncthreads();
      compute(lds, lds + BM * 64);
      __syncthreads();
    }
  }

  const int rb = (lane >> 4) << 2;
  const int cb = lane & 15;

  if constexpr (EPI == EPI_BD) {
    // raw BD (pre-scaled) into flat-padded buffer pitch 1025: idx = 1025q + 1 + t
    #pragma unroll
    for (int fm = 0; fm < FM; ++fm)
      #pragma unroll
      for (int fn = 0; fn < FN; ++fn)
        #pragma unroll
        for (int r = 0; r < 4; ++r) {
          int row = m0 + wM * TM + fm * 16 + rb + r;   // 0..8191 (b*512+q)
          int t   = n0 + wN * TN + fn * 16 + cb;
          int bb = row >> 9, q = row & 511;
          u16* Sp = p.S + (size_t)(bb * 8 + h) * 524800;
          Sp[(size_t)q * 1025 + 1 + t] = f2bf(acc[fm][fn][r] * 0.125f);
          if (t == 0 && q > 0) Sp[(size_t)q * 1025] = 0;  // rel-shift pad zero
        }
  } else if constexpr (EPI == EPI_QUV) {
    #pragma unroll
    for (int fm = 0; fm < FM; ++fm)
      #pragma unroll
      for (int fn = 0; fn < FN; ++fn)
        #pragma unroll
        for (int r = 0; r < 4; ++r) {
          int row = m0 + wM * TM + fm * 16 + rb + r;
          int col = n0 + wN * TN + fn * 16 + cb;
          size_t o = (size_t)row * p.ldc + col;
          float x = acc[fm][fn][r];
          p.C[o]  = f2bf(x + p.bias[col]);
          p.C2[o] = f2bf(x + p.bias2[col]);
        }
  } else {
    u16* Cb = p.C + (long long)b * p.sCb + (long long)h * p.sCh;
    #pragma unroll
    for (int fm = 0; fm < FM; ++fm)
      #pragma unroll
      for (int fn = 0; fn < FN; ++fn)
        #pragma unroll
        for (int r = 0; r < 4; ++r) {
          int row = m0 + wM * TM + fm * 16 + rb + r;
          int col = n0 + wN * TN + fn * 16 + cb;
          float x = acc[fm][fn][r];
          if (p.bias) x += p.bias[col];
          if constexpr (EPI == EPI_SIG)  x = 1.f / (1.f + __expf(-x));
          if constexpr (EPI == EPI_TANH) { float e = __expf(-2.f * fabsf(x)); float t = (1.f - e) / (1.f + e); x = copysignf(t, x); }
          if constexpr (EPI == EPI_GELU) x = 0.5f * x * (1.f + erff(x * 0.70710678118654752f));
          Cb[(size_t)row * p.ldc + col] = f2bf(x);
        }
  }
}

// ---------------- fused flash attention (q-tile 256, double-buffered, stage-early) ----------------
// grid (TQ/256, B*H). scores = AC*0.125 + BDflat (pre-scaled); online softmax; PV; Y=O/l.
__launch_bounds__(256, 1)
__global__ void fattn_k(const u16* __restrict__ qU, const u16* __restrict__ kv,
                        const u16* __restrict__ vT, const u16* __restrict__ BD,
                        u16* __restrict__ Y) {
  __shared__ __align__(16) u16 sQ[256 * 64];        // 32KB
  __shared__ __align__(16) u16 sBuf[2 * 24576];     // per buf: K[4096] V[4096] BD/P[16384] = 48KB

  const int tid = threadIdx.x, w = tid >> 6, lane = tid & 63;
  const int q0 = blockIdx.x * 256;
  const int bz = blockIdx.y, b = bz >> 3, h = bz & 7;
  const int cq = lane & 15, kb = lane >> 4;
  const u16* Sb = BD + (size_t)bz * 524800;

  auto stage = [&](int j0, u16* buf) {
    u16* sK_ = buf; u16* sV_ = buf + 4096; u16* sB_ = buf + 8192;
    #pragma unroll
    for (int i = 0; i < 2; ++i) {
      int c = i * 256 + tid, row = c >> 3, cc = c & 7, sc = cc ^ (row & 7);
      gload_lds16(kv + ((size_t)(b * 1024 + j0 + row)) * 1024 + h * 64 + sc * 8,
                  sK_ + (size_t)(i * 4 + w) * 512);
      gload_lds16(vT + (size_t)bz * 65536 + (size_t)row * 1024 + j0 + sc * 8,
                  sV_ + (size_t)(i * 4 + w) * 512);
    }
    #pragma unroll
    for (int i = 0; i < 8; ++i) {
      int c = i * 256 + tid, row = c >> 3, cc = c & 7, sc = cc ^ (row & 7);
      gload_lds16(Sb + 512 + (size_t)(q0 + row) * 1024 + j0 + sc * 8,
                  sB_ + (size_t)(i * 4 + w) * 512);
    }
  };

  // stage Q (256x64) + tile 0
  #pragma unroll
  for (int i = 0; i < 8; ++i) {
    int c = i * 256 + tid, row = c >> 3, cc = c & 7, sc = cc ^ (row & 7);
    gload_lds16(qU + ((size_t)(b * 512 + q0 + row)) * 512 + h * 64 + sc * 8,
                sQ + (size_t)(i * 4 + w) * 512);
  }
  stage(0, sBuf);
  __syncthreads();

  float m_s[4][4], l_s[4][4];
  f4 O[4][4];
  #pragma unroll
  for (int fm = 0; fm < 4; ++fm)
    #pragma unroll
    for (int r = 0; r < 4; ++r) { m_s[fm][r] = -1e30f; l_s[fm][r] = 0.f; }
  #pragma unroll
  for (int fm = 0; fm < 4; ++fm)
    #pragma unroll
    for (int fd = 0; fd < 4; ++fd) O[fm][fd] = f4{0.f, 0.f, 0.f, 0.f};

  for (int it = 0; it < 16; ++it) {
    u16* buf = sBuf + (size_t)(it & 1) * 24576;
    u16* sK_ = buf; u16* sV_ = buf + 4096; u16* sPB_ = buf + 8192;
    if (it < 15) stage((it + 1) * 64, sBuf + (size_t)((it + 1) & 1) * 24576);

    // AC MFMA: per wave 64 q-rows x 64 j
    f4 acc[4][4];
    #pragma unroll
    for (int fm = 0; fm < 4; ++fm)
      #pragma unroll
      for (int fn = 0; fn < 4; ++fn) acc[fm][fn] = f4{0.f, 0.f, 0.f, 0.f};
    #pragma unroll
    for (int kk = 0; kk < 2; ++kk) {
      int gc = kk * 4 + kb;
      s16x8 av[4], bv[4];
      #pragma unroll
      for (int fm = 0; fm < 4; ++fm) {
        int r = w * 64 + fm * 16 + cq;
        av[fm] = *(const s16x8*)(sQ + r * 64 + ((gc ^ (r & 7)) << 3));
      }
      #pragma unroll
      for (int fn = 0; fn < 4; ++fn) {
        int r = fn * 16 + cq;
        bv[fn] = *(const s16x8*)(sK_ + r * 64 + ((gc ^ (r & 7)) << 3));
      }
      #pragma unroll
      for (int fm = 0; fm < 4; ++fm)
        #pragma unroll
        for (int fn = 0; fn < 4; ++fn)
          acc[fm][fn] = __builtin_amdgcn_mfma_f32_16x16x32_bf16(av[fm], bv[fn], acc[fm][fn], 0, 0, 0);
    }

    // scores + online softmax; P overwrites BD slots (per-slot single owner thread)
    float alr[4][4];
    #pragma unroll
    for (int fm = 0; fm < 4; ++fm) {
      #pragma unroll
      for (int r = 0; r < 4; ++r) {
        int row = w * 64 + fm * 16 + kb * 4 + r;
        int sw = row & 7;
        float sv[4];
        float tm = -1e30f;
        #pragma unroll
        for (int fn = 0; fn < 4; ++fn) {
          int j = fn * 16 + cq;
          float bd = bf2f(sPB_[row * 64 + (((j >> 3) ^ sw) << 3) + (j & 7)]);
          float s = acc[fm][fn][r] * 0.125f + bd;
          sv[fn] = s;
          tm = fmaxf(tm, s);
        }
        tm = fmaxf(tm, __shfl_xor(tm, 1));
        tm = fmaxf(tm, __shfl_xor(tm, 2));
        tm = fmaxf(tm, __shfl_xor(tm, 4));
        tm = fmaxf(tm, __shfl_xor(tm, 8));
        float mo = m_s[fm][r];
        float mn = fmaxf(mo, tm);
        float al = __expf(mo - mn);
        m_s[fm][r] = mn;
        float ps = 0.f;
        #pragma unroll
        for (int fn = 0; fn < 4; ++fn) {
          float pp = __expf(sv[fn] - mn);
          ps += pp;
          int j = fn * 16 + cq;
          sPB_[row * 64 + (((j >> 3) ^ sw) << 3) + (j & 7)] = f2bf(pp);
        }
        l_s[fm][r] = l_s[fm][r] * al + ps;
        alr[fm][r] = al;
      }
    }
    #pragma unroll
    for (int fm = 0; fm < 4; ++fm)
      #pragma unroll
      for (int fd = 0; fd < 4; ++fd)
        #pragma unroll
        for (int r = 0; r < 4; ++r) O[fm][fd][r] *= alr[fm][r];

    // PV MFMA (P rows are wave-local; V staged last iter): no barrier needed before
    #pragma unroll
    for (int kk = 0; kk < 2; ++kk) {
      int m = kk * 4 + kb;
      s16x8 pa[4], vb[4];
      #pragma unroll
      for (int fm = 0; fm < 4; ++fm) {
        int r = w * 64 + fm * 16 + cq;
        pa[fm] = *(const s16x8*)(sPB_ + r * 64 + ((m ^ (r & 7)) << 3));
      }
      #pragma unroll
      for (int fd = 0; fd < 4; ++fd) {
        int rd = fd * 16 + cq;
        vb[fd] = *(const s16x8*)(sV_ + rd * 64 + ((m ^ (rd & 7)) << 3));
      }
      #pragma unroll
      for (int fm = 0; fm < 4; ++fm)
        #pragma unroll
        for (int fd = 0; fd < 4; ++fd)
          O[fm][fd] = __builtin_amdgcn_mfma_f32_16x16x32_bf16(pa[fm], vb[fd], O[fm][fd], 0, 0, 0);
    }
    __syncthreads();   // drains next-tile loads + read-safety for buffer reuse
  }

  // normalize + write Y[(b*512+q)*512 + h*64 + d]
  #pragma unroll
  for (int fm = 0; fm < 4; ++fm)
    #pragma unroll
    for (int r = 0; r < 4; ++r) {
      float l = l_s[fm][r];
      l += __shfl_xor(l, 1); l += __shfl_xor(l, 2);
      l += __shfl_xor(l, 4); l += __shfl_xor(l, 8);
      l_s[fm][r] = 1.f / l;
    }
  #pragma unroll
  for (int fm = 0; fm < 4; ++fm)
    #pragma unroll
    for (int fd = 0; fd < 4; ++fd)
      #pragma unroll
      for (int r = 0; r < 4; ++r) {
        int row = q0 + w * 64 + fm * 16 + kb * 4 + r;
        int col = h * 64 + fd * 16 + cq;
        Y[(size_t)(b * 512 + row) * 512 + col] = f2bf(O[fm][fd][r] * l_s[fm][r]);
      }
}

// ---------------- LayerNorm (D=512), fp32 in -> bf16 out ----------------
__launch_bounds__(256)
__global__ void ln_k(const float* __restrict__ x, const float* __restrict__ g,
                     const float* __restrict__ be, u16* __restrict__ out) {
  int row  = blockIdx.x * 4 + (threadIdx.x >> 6);
  int lane = threadIdx.x & 63;
  const float* xr = x + (size_t)row * 512 + lane * 8;
  f4 v0 = *(const f4*)xr;
  f4 v1 = *(const f4*)(xr + 4);
  float s = 0.f, q = 0.f;
  #pragma unroll
  for (int i = 0; i < 4; ++i) { s += v0[i] + v1[i]; q += v0[i]*v0[i] + v1[i]*v1[i]; }
  #pragma unroll
  for (int o = 32; o > 0; o >>= 1) { s += __shfl_xor(s, o); q += __shfl_xor(q, o); }
  float mu = s * (1.f / 512.f);
  float rs = rsqrtf(q * (1.f / 512.f) - mu * mu + 1e-5f);
  int c = lane * 8;
  u16x8 o;
  #pragma unroll
  for (int i = 0; i < 8; ++i) {
    float xx = (i < 4) ? v0[i] : v1[i - 4];
    o[i] = f2bf((xx - mu) * rs * g[c + i] + be[c + i]);
  }
  *(u16x8*)(out + (size_t)row * 512 + c) = o;
}

// ---------------- transpose helpers: src fp32 [R][C] -> dst bf16 [C][R] ----------------
__device__ __forceinline__ void tbody(float (*t)[65], const float* src, u16* dst,
                                      int R, int C, int bx, int by, int tid) {
  int c0 = bx * 64, r0 = by * 64;
  #pragma unroll
  for (int i = 0; i < 4; ++i) {
    int r = i * 16 + (tid >> 4);
    int c4 = (tid & 15) * 4;
    f4 v = *(const f4*)(src + (size_t)(r0 + r) * C + c0 + c4);
    t[r][c4] = v.x; t[r][c4 + 1] = v.y; t[r][c4 + 2] = v.z; t[r][c4 + 3] = v.w;
  }
  __syncthreads();
  #pragma unroll
  for (int i = 0; i < 2; ++i) {
    int id = i * 256 + tid;
    int rr = id >> 3, c8 = (id & 7) * 8;
    u16x8 o;
    #pragma unroll
    for (int j = 0; j < 8; ++j) o[j] = f2bf(t[c8 + j][rr]);
    *(u16x8*)(dst + (size_t)(c0 + rr) * R + r0 + c8) = o;
  }
}

__launch_bounds__(256)
__global__ void tsq_k(const float* aW, const float* g1W, const float* g2W, u16* wT) {
  __shared__ float t[64][65];
  int z = blockIdx.z;
  const int lut[6] = {0, 2, 1, 3, 4, 5};
  const float* src; u16* dst;
  if (z < 5)       { src = aW  + (size_t)z * 262144;        dst = wT + (size_t)z * 262144; }
  else if (z < 11) { int j = z - 5;  src = g1W + (size_t)j * 262144; dst = wT + (size_t)(5 + lut[j]) * 262144; }
  else             { int j = z - 11; src = g2W + (size_t)j * 262144; dst = wT + (size_t)(11 + lut[j]) * 262144; }
  tbody(t, src, dst, 512, 512, blockIdx.x, blockIdx.y, threadIdx.x);
}

__launch_bounds__(256)
__global__ void tgen_k(const float* src, u16* dst, int R, int C) {
  __shared__ float t[64][65];
  tbody(t, src, dst, R, C, blockIdx.x, blockIdx.y, threadIdx.x);
}

// ---------------- v transpose: kv cols 512.. -> vT[b,h][64][1024] ----------------
__launch_bounds__(256)
__global__ void vtrans_k(const u16* kv, u16* vT) {
  int jt = blockIdx.x, h = blockIdx.y, b = blockIdx.z;
  __shared__ u16 t[64][72];
  int tid = threadIdx.x;
  const u16* src = kv + ((size_t)b * 1024 + jt * 64) * 1024 + 512 + h * 64;
  #pragma unroll
  for (int i = 0; i < 2; ++i) {
    int id = i * 256 + tid;
    int r = id >> 3, c = (id & 7) * 8;
    u16x8 v = *(const u16x8*)(src + (size_t)r * 1024 + c);
    #pragma unroll
    for (int j = 0; j < 8; ++j) t[r][c + j] = v[j];
  }
  __syncthreads();
  u16* dst = vT + (size_t)(b * 8 + h) * 65536 + (size_t)jt * 64;
  #pragma unroll
  for (int i = 0; i < 2; ++i) {
    int id = i * 256 + tid;
    int d = id >> 3, c = (id & 7) * 8;
    u16x8 o;
    #pragma unroll
    for (int j = 0; j < 8; ++j) o[j] = t[c + j][d];
    *(u16x8*)(dst + (size_t)d * 1024 + c) = o;
  }
}

// ---------------- small elementwise ----------------
__launch_bounds__(256)
__global__ void conv_k(const float* in, u16* out, int n8) {
  int i = blockIdx.x * 256 + threadIdx.x;
  if (i >= n8) return;
  const float* p = in + (size_t)i * 8;
  f4 a = *(const f4*)p, b = *(const f4*)(p + 4);
  u16x8 o;
  #pragma unroll
  for (int j = 0; j < 4; ++j) { o[j] = f2bf(a[j]); o[4 + j] = f2bf(b[j]); }
  *(u16x8*)(out + (size_t)i * 8) = o;
}

__launch_bounds__(256)
__global__ void bias_k(const float* g1b, const float* g2b, float* b1, float* b2) {
  int i = blockIdx.x * 256 + threadIdx.x;
  if (i < 1024) { b1[i] = (i < 512) ? 0.f : -g1b[i - 512]; b2[i] = (i < 512) ? 0.f : -g2b[i - 512]; }
}

__launch_bounds__(256)
__global__ void rx_k(const u16* rz, const float* x, u16* rx) {
  int i = blockIdx.x * 256 + threadIdx.x;
  int m = i >> 6, d8 = (i & 63) << 3;
  u16x8 rv = *(const u16x8*)(rz + (size_t)m * 1024 + d8);
  const float* xp = x + (size_t)m * 512 + d8;
  f4 x0 = *(const f4*)xp, x1 = *(const f4*)(xp + 4);
  u16x8 o;
  #pragma unroll
  for (int j = 0; j < 4; ++j) { o[j] = f2bf(bf2f(rv[j]) * x0[j]); o[4 + j] = f2bf(bf2f(rv[4 + j]) * x1[j]); }
  *(u16x8*)(rx + (size_t)m * 512 + d8) = o;
}

__launch_bounds__(256)
__global__ void comb_k(const u16* rz, const u16* hg, const float* x, float* of, u16* ob) {
  int i = blockIdx.x * 256 + threadIdx.x;
  int m = i >> 6, d8 = (i & 63) << 3;
  u16x8 zv = *(const u16x8*)(rz + (size_t)m * 1024 + 512 + d8);
  u16x8 hv = *(const u16x8*)(hg + (size_t)m * 512 + d8);
  const float* xp = x + (size_t)m * 512 + d8;
  f4 x0 = *(const f4*)xp, x1 = *(const f4*)(xp + 4);
  f4 o0, o1; u16x8 obv;
  #pragma unroll
  for (int j = 0; j < 4; ++j) {
    float z = bf2f(zv[j]), hh = bf2f(hv[j]);
    float r = (1.f - z) * x0[j] + z * hh; o0[j] = r; obv[j] = f2bf(r);
  }
  #pragma unroll
  for (int j = 0; j < 4; ++j) {
    float z = bf2f(zv[4 + j]), hh = bf2f(hv[4 + j]);
    float r = (1.f - z) * x1[j] + z * hh; o1[j] = r; obv[4 + j] = f2bf(r);
  }
  float* op = of + (size_t)m * 512 + d8;
  *(f4*)op = o0; *(f4*)(op + 4) = o1;
  if (ob) *(u16x8*)(ob + (size_t)m * 512 + d8) = obv;
}

// ---------------- host ----------------
extern "C" void kernel_launch(void* const* d_in, const int* in_sizes, int n_in,
                              void* d_out, int out_size, void* d_ws, size_t ws_size,
                              hipStream_t stream) {
  const float* query = (const float*)d_in[0];
  const float* key   = (const float*)d_in[1];
  const float* pos   = (const float*)d_in[2];
  const float* U     = (const float*)d_in[3];
  const float* V     = (const float*)d_in[4];
  const float* attnW = (const float*)d_in[5];
  const float* ln1g  = (const float*)d_in[6];
  const float* ln1b  = (const float*)d_in[7];
  const float* ln2g  = (const float*)d_in[8];
  const float* ln2b  = (const float*)d_in[9];
  const float* g1W   = (const float*)d_in[10];
  const float* g1b   = (const float*)d_in[11];
  const float* g2W   = (const float*)d_in[12];
  const float* g2b   = (const float*)d_in[13];
  const float* fcW1  = (const float*)d_in[14];
  const float* fcb1  = (const float*)d_in[15];
  const float* fcW2  = (const float*)d_in[16];
  const float* fcb2  = (const float*)d_in[17];
  float* outp = (float*)d_out;

  char* base = (char*)d_ws;
  size_t off = 0;
  auto alloc = [&](size_t bytes) -> char* {
    char* p = base + off;
    off += (bytes + 255) & ~(size_t)255;
    return p;
  };

  u16* wT     = (u16*)alloc(17ull * 262144 * 2);
  u16* fc1T   = (u16*)alloc(2048ull * 512 * 2);
  u16* fc2T   = (u16*)alloc(2048ull * 512 * 2);
  u16* posb   = (u16*)alloc(1024ull * 512 * 2);
  u16* pbf    = (u16*)alloc(1024ull * 512 * 2);
  float* bias1 = (float*)alloc(1024 * 4);
  float* bias2 = (float*)alloc(1024 * 4);
  u16* nq     = (u16*)alloc(8192ull * 512 * 2);    // reused later as Y
  u16* nk     = (u16*)alloc(16384ull * 512 * 2);   // reused later as vT
  u16* xq     = (u16*)alloc(8192ull * 512 * 2);
  u16* qU     = (u16*)alloc(8192ull * 512 * 2);    // qU+qV reused later as out1 (fp32)
  u16* qV     = (u16*)alloc(8192ull * 512 * 2);
  u16* kv     = (u16*)alloc(16384ull * 1024 * 2);
  u16* y1     = (u16*)alloc(8192ull * 512 * 2);
  u16* ob1    = (u16*)alloc(8192ull * 512 * 2);
  u16* S      = (u16*)alloc(128ull * 524800 * 2 + 4096);  // flat-padded raw BD [B*H][512*1025]
  if (off > ws_size) return;

  // overlays
  u16* Y = nq;
  u16* vT = nk;
  float* out1f = (float*)qU;
  u16* rz1 = S;
  u16* rx1 = S + 8388608;
  u16* hg1 = rx1 + 4194304;
  u16* h2  = hg1 + 4194304;
  u16* e1  = h2 + 4194304;
  u16* y2  = e1 + 16777216;
  u16* rz2 = y2 + 4194304;
  u16* rx2 = rz2 + 8388608;
  u16* hg2 = rx2 + 4194304;

  // --- prep ---
  bias_k<<<dim3(4), dim3(256), 0, stream>>>(g1b, g2b, bias1, bias2);
  tsq_k<<<dim3(8, 8, 17), dim3(256), 0, stream>>>(attnW, g1W, g2W, wT);
  tgen_k<<<dim3(32, 8), dim3(256), 0, stream>>>(fcW1, fc1T, 512, 2048);
  tgen_k<<<dim3(8, 32), dim3(256), 0, stream>>>(fcW2, fc2T, 2048, 512);
  conv_k<<<dim3(256), dim3(256), 0, stream>>>(pos, posb, 65536);
  conv_k<<<dim3(2048), dim3(256), 0, stream>>>(query, xq, 524288);
  ln_k<<<dim3(2048), dim3(256), 0, stream>>>(query, ln1g, ln1b, nq);
  ln_k<<<dim3(4096), dim3(256), 0, stream>>>(key, ln1g, ln1b, nk);

  // --- projections ---
  { GemmP p{}; p.A = nq; p.B = wT; p.K1 = 512; p.lda = 512; p.ldb = 512; p.H = 1;
    p.C = qU; p.C2 = qV; p.ldc = 512; p.bias = U; p.bias2 = V;
    gemm_k<128,128,EPI_QUV,1><<<dim3(64,4,1), dim3(256), 0, stream>>>(p); }
  { GemmP p{}; p.A = nk; p.B = wT + 1ull*262144; p.K1 = 512; p.lda = 512; p.ldb = 512; p.H = 1;
    p.C = kv; p.ldc = 1024;
    gemm_k<128,128,EPI_BF16,0><<<dim3(128,8,1), dim3(256), 0, stream>>>(p); }
  { GemmP p{}; p.A = posb; p.B = wT + 3ull*262144; p.K1 = 512; p.lda = 512; p.ldb = 512; p.H = 1;
    p.C = pbf; p.ldc = 512;
    gemm_k<128,128,EPI_BF16,1><<<dim3(8,4,1), dim3(256), 0, stream>>>(p); }
  vtrans_k<<<dim3(16, 8, 16), dim3(256), 0, stream>>>(kv, vT);

  // --- raw BD into flat-padded buffer ---
  { GemmP p{}; p.A = qV; p.lda = 512; p.sAh = 64;
    p.B = pbf; p.ldb = 512; p.sBh = 64; p.K1 = 64; p.H = 8; p.S = S;
    gemm_k<128,128,EPI_BD,0><<<dim3(64,8,8), dim3(256), 0, stream>>>(p); }

  // --- fused attention: AC + BD + softmax + PV ---
  fattn_k<<<dim3(2, 128), dim3(256), 0, stream>>>(qU, kv, vT, S, Y);

  { GemmP p{}; p.A = Y; p.B = wT + 4ull*262144; p.K1 = 512; p.lda = 512; p.ldb = 512; p.H = 1;
    p.C = y1; p.ldc = 512;
    gemm_k<128,128,EPI_GELU,1><<<dim3(64,4,1), dim3(256), 0, stream>>>(p); }

  // --- gate 1 ---
  { GemmP p{}; p.A = y1; p.B = wT + 5ull*262144; p.K1 = 512;
    p.A2 = xq; p.B2 = wT + 7ull*262144; p.K2 = 512;
    p.lda = 512; p.ldb = 512; p.H = 1; p.C = rz1; p.ldc = 1024; p.bias = bias1;
    gemm_k<128,128,EPI_SIG,1><<<dim3(64,8,1), dim3(256), 0, stream>>>(p); }
  rx_k<<<dim3(2048), dim3(256), 0, stream>>>(rz1, query, rx1);
  { GemmP p{}; p.A = y1; p.B = wT + 9ull*262144; p.K1 = 512;
    p.A2 = rx1; p.B2 = wT + 10ull*262144; p.K2 = 512;
    p.lda = 512; p.ldb = 512; p.H = 1; p.C = hg1; p.ldc = 512;
    gemm_k<128,128,EPI_TANH,1><<<dim3(64,4,1), dim3(256), 0, stream>>>(p); }
  comb_k<<<dim3(2048), dim3(256), 0, stream>>>(rz1, hg1, query, out1f, ob1);

  // --- FFN ---
  ln_k<<<dim3(2048), dim3(256), 0, stream>>>(out1f, ln2g, ln2b, h2);
  { GemmP p{}; p.A = h2; p.B = fc1T; p.K1 = 512; p.lda = 512; p.ldb = 512; p.H = 1;
    p.C = e1; p.ldc = 2048; p.bias = fcb1;
    gemm_k<128,128,EPI_GELU,0><<<dim3(64,16,1), dim3(256), 0, stream>>>(p); }
  { GemmP p{}; p.A = e1; p.B = fc2T; p.K1 = 2048; p.lda = 2048; p.ldb = 2048; p.H = 1;
    p.C = y2; p.ldc = 512; p.bias = fcb2;
    gemm_k<128,128,EPI_GELU,1><<<dim3(64,4,1), dim3(256), 0, stream>>>(p); }

  // --- gate 2 ---
  { GemmP p{}; p.A = y2; p.B = wT + 11ull*262144; p.K1 = 512;
    p.A2 = ob1; p.B2 = wT + 13ull*262144; p.K2 = 512;
    p.lda = 512; p.ldb = 512; p.H = 1; p.C = rz2; p.ldc = 1024; p.bias = bias2;
    gemm_k<128,128,EPI_SIG,1><<<dim3(64,8,1), dim3(256), 0, stream>>>(p); }
  rx_k<<<dim3(2048), dim3(256), 0, stream>>>(rz2, out1f, rx2);
  { GemmP p{}; p.A = y2; p.B = wT + 15ull*262144; p.K1 = 512;
    p.A2 = rx2; p.B2 = wT + 16ull*262144; p.K2 = 512;
    p.lda = 512; p.ldb = 512; p.H = 1; p.C = hg2; p.ldc = 512;
    gemm_k<128,128,EPI_TANH,1><<<dim3(64,4,1), dim3(256), 0, stream>>>(p); }
  comb_k<<<dim3(2048), dim3(256), 0, stream>>>(rz2, hg2, out1f, outp, (u16*)nullptr);
}

// Round 8
// 448.088 us; speedup vs baseline: 1.1287x; 1.1287x over previous
//
#include <hip/hip_runtime.h>
#include <hip/hip_bf16.h>

typedef unsigned short u16;
typedef __attribute__((ext_vector_type(4))) float f4;
typedef __attribute__((ext_vector_type(8))) short s16x8;
typedef __attribute__((ext_vector_type(8))) unsigned short u16x8;

__device__ __forceinline__ u16 f2bf(float x){
  unsigned u = __float_as_uint(x);
  u += 0x7fffu + ((u >> 16) & 1u);
  return (u16)(u >> 16);
}
__device__ __forceinline__ float bf2f(u16 h){ return __uint_as_float(((unsigned)h) << 16); }

__device__ __forceinline__ void gload_lds16(const u16* g, u16* l){
  __builtin_amdgcn_global_load_lds((__attribute__((address_space(1))) void*)g,
                                   (__attribute__((address_space(3))) void*)l, 16, 0, 0);
}

// ---------------- GEMM ----------------
// C[M,N] = A1[M,K1] @ B1t[N,K1]^T + A2[M,K2] @ B2t[N,K2]^T, bf16 in, fp32 acc.
struct GemmP {
  const u16* A; const u16* B;
  const u16* A2; const u16* B2;
  int K1, K2, lda, ldb, H;
  long long sAb, sAh, sBb, sBh;
  u16* C; long long sCb, sCh; int ldc;
  u16* C2;
  const float* bias; const float* bias2;
  u16* S;
};

enum { EPI_BF16=0, EPI_QUV=1, EPI_SIG=2, EPI_TANH=3, EPI_GELU=4, EPI_BD=5 };

// DB=1: 2-phase stage-early double-buffered pipeline (for small-grid / 1-2 blk/CU GEMMs)
template<int BM, int BN, int EPI, int DB>
__launch_bounds__(256)
__global__ void gemm_k(GemmP p) {
  constexpr int WN = (BN >= 128) ? 2 : 1;
  constexpr int WM = 4 / WN;
  constexpr int TM = BM / WM, TN = BN / WN;
  constexpr int FM = TM / 16, FN = TN / 16;
  constexpr int BUFE = (BM + BN) * 64;

  __shared__ __align__(16) u16 lds[BUFE * (DB ? 2 : 1)];

  const int tid = threadIdx.x;
  const int w = tid >> 6, lane = tid & 63;
  const int bz = blockIdx.z;
  const int b = bz / p.H, h = bz - b * p.H;
  const int m0 = blockIdx.x * BM, n0 = blockIdx.y * BN;

  const u16* Ab0 = p.A + (long long)b * p.sAb + (long long)h * p.sAh + (long long)m0 * p.lda;
  const u16* Bb0 = p.B + (long long)b * p.sBb + (long long)h * p.sBh + (long long)n0 * p.ldb;
  const u16* Ab1 = p.A2 ? p.A2 + (long long)m0 * p.lda : (const u16*)0;
  const u16* Bb1 = p.B2 ? p.B2 + (long long)n0 * p.ldb : (const u16*)0;

  f4 acc[FM][FN];
  #pragma unroll
  for (int i = 0; i < FM; ++i)
    #pragma unroll
    for (int j = 0; j < FN; ++j) acc[i][j] = f4{0.f, 0.f, 0.f, 0.f};

  const int s1 = p.K1 >> 6;
  const int st = s1 + (p.K2 >> 6);
  const int wM = w / WN, wN = w - wM * WN;

  auto stage = [&](int s, u16* lA_, u16* lB_) {
    const u16* Ab; const u16* Bb; int k0;
    if (s < s1) { Ab = Ab0; Bb = Bb0; k0 = s << 6; }
    else        { Ab = Ab1; Bb = Bb1; k0 = (s - s1) << 6; }
    #pragma unroll
    for (int i = 0; i < (BM >> 5); ++i) {
      int c = i * 256 + tid, row = c >> 3, cc = c & 7, sc = cc ^ (row & 7);
      gload_lds16(Ab + (long long)row * p.lda + k0 + sc * 8, lA_ + (size_t)(i * 4 + w) * 512);
    }
    #pragma unroll
    for (int i = 0; i < (BN >> 5); ++i) {
      int c = i * 256 + tid, row = c >> 3, cc = c & 7, sc = cc ^ (row & 7);
      gload_lds16(Bb + (long long)row * p.ldb + k0 + sc * 8, lB_ + (size_t)(i * 4 + w) * 512);
    }
  };

  auto compute = [&](const u16* lA_, const u16* lB_) {
    #pragma unroll
    for (int kk = 0; kk < 2; ++kk) {
      const int kb = lane >> 4;
      const int gc = kk * 4 + kb;
      s16x8 av[FM], bv[FN];
      #pragma unroll
      for (int fm = 0; fm < FM; ++fm) {
        int r = wM * TM + fm * 16 + (lane & 15);
        av[fm] = *(const s16x8*)(lA_ + r * 64 + ((gc ^ (r & 7)) << 3));
      }
      #pragma unroll
      for (int fn = 0; fn < FN; ++fn) {
        int r = wN * TN + fn * 16 + (lane & 15);
        bv[fn] = *(const s16x8*)(lB_ + r * 64 + ((gc ^ (r & 7)) << 3));
      }
      #pragma unroll
      for (int fm = 0; fm < FM; ++fm)
        #pragma unroll
        for (int fn = 0; fn < FN; ++fn)
          acc[fm][fn] = __builtin_amdgcn_mfma_f32_16x16x32_bf16(av[fm], bv[fn], acc[fm][fn], 0, 0, 0);
    }
  };

  if constexpr (DB) {
    stage(0, lds, lds + BM * 64);
    __syncthreads();
    for (int s = 0; s < st; ++s) {
      u16* cur = lds + (size_t)(s & 1) * BUFE;
      if (s + 1 < st) {
        u16* nxt = lds + (size_t)((s + 1) & 1) * BUFE;
        stage(s + 1, nxt, nxt + BM * 64);
      }
      compute(cur, cur + BM * 64);
      __syncthreads();   // drains staged loads (issued before compute) + read-safety
    }
  } else {
    for (int s = 0; s < st; ++s) {
      stage(s, lds, lds + BM * 64);
      __syncthreads();
      compute(lds, lds + BM * 64);
      __syncthreads();
    }
  }

  const int rb = (lane >> 4) << 2;
  const int cb = lane & 15;

  if constexpr (EPI == EPI_BD) {
    // raw BD (pre-scaled) into flat-padded buffer pitch 1025: idx = 1025q + 1 + t
    #pragma unroll
    for (int fm = 0; fm < FM; ++fm)
      #pragma unroll
      for (int fn = 0; fn < FN; ++fn)
        #pragma unroll
        for (int r = 0; r < 4; ++r) {
          int row = m0 + wM * TM + fm * 16 + rb + r;   // 0..8191 (b*512+q)
          int t   = n0 + wN * TN + fn * 16 + cb;
          int bb = row >> 9, q = row & 511;
          u16* Sp = p.S + (size_t)(bb * 8 + h) * 524800;
          Sp[(size_t)q * 1025 + 1 + t] = f2bf(acc[fm][fn][r] * 0.125f);
          if (t == 0 && q > 0) Sp[(size_t)q * 1025] = 0;  // rel-shift pad zero
        }
  } else if constexpr (EPI == EPI_QUV) {
    #pragma unroll
    for (int fm = 0; fm < FM; ++fm)
      #pragma unroll
      for (int fn = 0; fn < FN; ++fn)
        #pragma unroll
        for (int r = 0; r < 4; ++r) {
          int row = m0 + wM * TM + fm * 16 + rb + r;
          int col = n0 + wN * TN + fn * 16 + cb;
          size_t o = (size_t)row * p.ldc + col;
          float x = acc[fm][fn][r];
          p.C[o]  = f2bf(x + p.bias[col]);
          p.C2[o] = f2bf(x + p.bias2[col]);
        }
  } else {
    u16* Cb = p.C + (long long)b * p.sCb + (long long)h * p.sCh;
    #pragma unroll
    for (int fm = 0; fm < FM; ++fm)
      #pragma unroll
      for (int fn = 0; fn < FN; ++fn)
        #pragma unroll
        for (int r = 0; r < 4; ++r) {
          int row = m0 + wM * TM + fm * 16 + rb + r;
          int col = n0 + wN * TN + fn * 16 + cb;
          float x = acc[fm][fn][r];
          if (p.bias) x += p.bias[col];
          if constexpr (EPI == EPI_SIG)  x = 1.f / (1.f + __expf(-x));
          if constexpr (EPI == EPI_TANH) { float e = __expf(-2.f * fabsf(x)); float t = (1.f - e) / (1.f + e); x = copysignf(t, x); }
          if constexpr (EPI == EPI_GELU) x = 0.5f * x * (1.f + erff(x * 0.70710678118654752f));
          Cb[(size_t)row * p.ldc + col] = f2bf(x);
        }
  }
}

// ---------------- fused flash attention (q-tile 128, double-buffered, stage-early) ----------------
// grid (TQ/128, B*H). scores = AC*0.125 + BDflat (pre-scaled); online softmax; PV; Y=O/l.
__launch_bounds__(256)
__global__ void fattn_k(const u16* __restrict__ qU, const u16* __restrict__ kv,
                        const u16* __restrict__ vT, const u16* __restrict__ BD,
                        u16* __restrict__ Y) {
  __shared__ __align__(16) u16 sQ[128 * 64];
  __shared__ __align__(16) u16 sBuf[2 * 16384];  // per buf: K[4096] V[4096] BD/P[8192]

  const int tid = threadIdx.x, w = tid >> 6, lane = tid & 63;
  const int q0 = blockIdx.x * 128;
  const int bz = blockIdx.y, b = bz >> 3, h = bz & 7;
  const int cq = lane & 15, kb = lane >> 4;
  const u16* Sb = BD + (size_t)bz * 524800;

  auto stage = [&](int j0, u16* buf) {
    u16* sK_ = buf; u16* sV_ = buf + 4096; u16* sB_ = buf + 8192;
    #pragma unroll
    for (int i = 0; i < 2; ++i) {
      int c = i * 256 + tid, row = c >> 3, cc = c & 7, sc = cc ^ (row & 7);
      gload_lds16(kv + ((size_t)(b * 1024 + j0 + row)) * 1024 + h * 64 + sc * 8,
                  sK_ + (size_t)(i * 4 + w) * 512);
      gload_lds16(vT + (size_t)bz * 65536 + (size_t)row * 1024 + j0 + sc * 8,
                  sV_ + (size_t)(i * 4 + w) * 512);
    }
    #pragma unroll
    for (int i = 0; i < 4; ++i) {
      int c = i * 256 + tid, row = c >> 3, cc = c & 7, sc = cc ^ (row & 7);
      gload_lds16(Sb + 512 + (size_t)(q0 + row) * 1024 + j0 + sc * 8,
                  sB_ + (size_t)(i * 4 + w) * 512);
    }
  };

  // stage Q + tile 0
  #pragma unroll
  for (int i = 0; i < 4; ++i) {
    int c = i * 256 + tid, row = c >> 3, cc = c & 7, sc = cc ^ (row & 7);
    gload_lds16(qU + ((size_t)(b * 512 + q0 + row)) * 512 + h * 64 + sc * 8,
                sQ + (size_t)(i * 4 + w) * 512);
  }
  stage(0, sBuf);
  __syncthreads();

  float m_s[2][4], l_s[2][4];
  f4 O[2][4];
  #pragma unroll
  for (int fm = 0; fm < 2; ++fm)
    #pragma unroll
    for (int r = 0; r < 4; ++r) { m_s[fm][r] = -1e30f; l_s[fm][r] = 0.f; }
  #pragma unroll
  for (int fm = 0; fm < 2; ++fm)
    #pragma unroll
    for (int fd = 0; fd < 4; ++fd) O[fm][fd] = f4{0.f, 0.f, 0.f, 0.f};

  for (int it = 0; it < 16; ++it) {
    u16* buf = sBuf + (size_t)(it & 1) * 16384;
    u16* sK_ = buf; u16* sV_ = buf + 4096; u16* sPB_ = buf + 8192;
    if (it < 15) stage((it + 1) * 64, sBuf + (size_t)((it + 1) & 1) * 16384);

    // AC MFMA: per wave 32 q-rows x 64 j
    f4 acc[2][4];
    #pragma unroll
    for (int fm = 0; fm < 2; ++fm)
      #pragma unroll
      for (int fn = 0; fn < 4; ++fn) acc[fm][fn] = f4{0.f, 0.f, 0.f, 0.f};
    #pragma unroll
    for (int kk = 0; kk < 2; ++kk) {
      int gc = kk * 4 + kb;
      s16x8 av[2], bv[4];
      #pragma unroll
      for (int fm = 0; fm < 2; ++fm) {
        int r = w * 32 + fm * 16 + cq;
        av[fm] = *(const s16x8*)(sQ + r * 64 + ((gc ^ (r & 7)) << 3));
      }
      #pragma unroll
      for (int fn = 0; fn < 4; ++fn) {
        int r = fn * 16 + cq;
        bv[fn] = *(const s16x8*)(sK_ + r * 64 + ((gc ^ (r & 7)) << 3));
      }
      #pragma unroll
      for (int fm = 0; fm < 2; ++fm)
        #pragma unroll
        for (int fn = 0; fn < 4; ++fn)
          acc[fm][fn] = __builtin_amdgcn_mfma_f32_16x16x32_bf16(av[fm], bv[fn], acc[fm][fn], 0, 0, 0);
    }

    // scores + online softmax; P overwrites BD slots (per-slot single owner thread)
    float alr[2][4];
    #pragma unroll
    for (int fm = 0; fm < 2; ++fm) {
      #pragma unroll
      for (int r = 0; r < 4; ++r) {
        int row = w * 32 + fm * 16 + kb * 4 + r;
        int sw = row & 7;
        float sv[4];
        float tm = -1e30f;
        #pragma unroll
        for (int fn = 0; fn < 4; ++fn) {
          int j = fn * 16 + cq;
          float bd = bf2f(sPB_[row * 64 + (((j >> 3) ^ sw) << 3) + (j & 7)]);
          float s = acc[fm][fn][r] * 0.125f + bd;
          sv[fn] = s;
          tm = fmaxf(tm, s);
        }
        tm = fmaxf(tm, __shfl_xor(tm, 1));
        tm = fmaxf(tm, __shfl_xor(tm, 2));
        tm = fmaxf(tm, __shfl_xor(tm, 4));
        tm = fmaxf(tm, __shfl_xor(tm, 8));
        float mo = m_s[fm][r];
        float mn = fmaxf(mo, tm);
        float al = __expf(mo - mn);
        m_s[fm][r] = mn;
        float ps = 0.f;
        #pragma unroll
        for (int fn = 0; fn < 4; ++fn) {
          float pp = __expf(sv[fn] - mn);
          ps += pp;
          int j = fn * 16 + cq;
          sPB_[row * 64 + (((j >> 3) ^ sw) << 3) + (j & 7)] = f2bf(pp);
        }
        l_s[fm][r] = l_s[fm][r] * al + ps;
        alr[fm][r] = al;
      }
    }
    #pragma unroll
    for (int fm = 0; fm < 2; ++fm)
      #pragma unroll
      for (int fd = 0; fd < 4; ++fd)
        #pragma unroll
        for (int r = 0; r < 4; ++r) O[fm][fd][r] *= alr[fm][r];

    // PV MFMA (P rows are wave-local; V staged last iter): no barrier needed before
    #pragma unroll
    for (int kk = 0; kk < 2; ++kk) {
      int m = kk * 4 + kb;
      s16x8 pa[2], vb[4];
      #pragma unroll
      for (int fm = 0; fm < 2; ++fm) {
        int r = w * 32 + fm * 16 + cq;
        pa[fm] = *(const s16x8*)(sPB_ + r * 64 + ((m ^ (r & 7)) << 3));
      }
      #pragma unroll
      for (int fd = 0; fd < 4; ++fd) {
        int rd = fd * 16 + cq;
        vb[fd] = *(const s16x8*)(sV_ + rd * 64 + ((m ^ (rd & 7)) << 3));
      }
      #pragma unroll
      for (int fm = 0; fm < 2; ++fm)
        #pragma unroll
        for (int fd = 0; fd < 4; ++fd)
          O[fm][fd] = __builtin_amdgcn_mfma_f32_16x16x32_bf16(pa[fm], vb[fd], O[fm][fd], 0, 0, 0);
    }
    __syncthreads();   // drains next-tile loads + read-safety for buffer reuse
  }

  // normalize + write Y[(b*512+q)*512 + h*64 + d]
  #pragma unroll
  for (int fm = 0; fm < 2; ++fm)
    #pragma unroll
    for (int r = 0; r < 4; ++r) {
      float l = l_s[fm][r];
      l += __shfl_xor(l, 1); l += __shfl_xor(l, 2);
      l += __shfl_xor(l, 4); l += __shfl_xor(l, 8);
      l_s[fm][r] = 1.f / l;
    }
  #pragma unroll
  for (int fm = 0; fm < 2; ++fm)
    #pragma unroll
    for (int fd = 0; fd < 4; ++fd)
      #pragma unroll
      for (int r = 0; r < 4; ++r) {
        int row = q0 + w * 32 + fm * 16 + kb * 4 + r;
        int col = h * 64 + fd * 16 + cq;
        Y[(size_t)(b * 512 + row) * 512 + col] = f2bf(O[fm][fd][r] * l_s[fm][r]);
      }
}

// ---------------- LayerNorm (D=512), fp32 in -> bf16 out ----------------
__launch_bounds__(256)
__global__ void ln_k(const float* __restrict__ x, const float* __restrict__ g,
                     const float* __restrict__ be, u16* __restrict__ out) {
  int row  = blockIdx.x * 4 + (threadIdx.x >> 6);
  int lane = threadIdx.x & 63;
  const float* xr = x + (size_t)row * 512 + lane * 8;
  f4 v0 = *(const f4*)xr;
  f4 v1 = *(const f4*)(xr + 4);
  float s = 0.f, q = 0.f;
  #pragma unroll
  for (int i = 0; i < 4; ++i) { s += v0[i] + v1[i]; q += v0[i]*v0[i] + v1[i]*v1[i]; }
  #pragma unroll
  for (int o = 32; o > 0; o >>= 1) { s += __shfl_xor(s, o); q += __shfl_xor(q, o); }
  float mu = s * (1.f / 512.f);
  float rs = rsqrtf(q * (1.f / 512.f) - mu * mu + 1e-5f);
  int c = lane * 8;
  u16x8 o;
  #pragma unroll
  for (int i = 0; i < 8; ++i) {
    float xx = (i < 4) ? v0[i] : v1[i - 4];
    o[i] = f2bf((xx - mu) * rs * g[c + i] + be[c + i]);
  }
  *(u16x8*)(out + (size_t)row * 512 + c) = o;
}

// ---------------- transpose helpers: src fp32 [R][C] -> dst bf16 [C][R] ----------------
__device__ __forceinline__ void tbody(float (*t)[65], const float* src, u16* dst,
                                      int R, int C, int bx, int by, int tid) {
  int c0 = bx * 64, r0 = by * 64;
  #pragma unroll
  for (int i = 0; i < 4; ++i) {
    int r = i * 16 + (tid >> 4);
    int c4 = (tid & 15) * 4;
    f4 v = *(const f4*)(src + (size_t)(r0 + r) * C + c0 + c4);
    t[r][c4] = v.x; t[r][c4 + 1] = v.y; t[r][c4 + 2] = v.z; t[r][c4 + 3] = v.w;
  }
  __syncthreads();
  #pragma unroll
  for (int i = 0; i < 2; ++i) {
    int id = i * 256 + tid;
    int rr = id >> 3, c8 = (id & 7) * 8;
    u16x8 o;
    #pragma unroll
    for (int j = 0; j < 8; ++j) o[j] = f2bf(t[c8 + j][rr]);
    *(u16x8*)(dst + (size_t)(c0 + rr) * R + r0 + c8) = o;
  }
}

__launch_bounds__(256)
__global__ void tsq_k(const float* aW, const float* g1W, const float* g2W, u16* wT) {
  __shared__ float t[64][65];
  int z = blockIdx.z;
  const int lut[6] = {0, 2, 1, 3, 4, 5};
  const float* src; u16* dst;
  if (z < 5)       { src = aW  + (size_t)z * 262144;        dst = wT + (size_t)z * 262144; }
  else if (z < 11) { int j = z - 5;  src = g1W + (size_t)j * 262144; dst = wT + (size_t)(5 + lut[j]) * 262144; }
  else             { int j = z - 11; src = g2W + (size_t)j * 262144; dst = wT + (size_t)(11 + lut[j]) * 262144; }
  tbody(t, src, dst, 512, 512, blockIdx.x, blockIdx.y, threadIdx.x);
}

__launch_bounds__(256)
__global__ void tgen_k(const float* src, u16* dst, int R, int C) {
  __shared__ float t[64][65];
  tbody(t, src, dst, R, C, blockIdx.x, blockIdx.y, threadIdx.x);
}

// ---------------- v transpose: kv cols 512.. -> vT[b,h][64][1024] ----------------
__launch_bounds__(256)
__global__ void vtrans_k(const u16* kv, u16* vT) {
  int jt = blockIdx.x, h = blockIdx.y, b = blockIdx.z;
  __shared__ u16 t[64][72];
  int tid = threadIdx.x;
  const u16* src = kv + ((size_t)b * 1024 + jt * 64) * 1024 + 512 + h * 64;
  #pragma unroll
  for (int i = 0; i < 2; ++i) {
    int id = i * 256 + tid;
    int r = id >> 3, c = (id & 7) * 8;
    u16x8 v = *(const u16x8*)(src + (size_t)r * 1024 + c);
    #pragma unroll
    for (int j = 0; j < 8; ++j) t[r][c + j] = v[j];
  }
  __syncthreads();
  u16* dst = vT + (size_t)(b * 8 + h) * 65536 + (size_t)jt * 64;
  #pragma unroll
  for (int i = 0; i < 2; ++i) {
    int id = i * 256 + tid;
    int d = id >> 3, c = (id & 7) * 8;
    u16x8 o;
    #pragma unroll
    for (int j = 0; j < 8; ++j) o[j] = t[c + j][d];
    *(u16x8*)(dst + (size_t)d * 1024 + c) = o;
  }
}

// ---------------- small elementwise ----------------
__launch_bounds__(256)
__global__ void conv_k(const float* in, u16* out, int n8) {
  int i = blockIdx.x * 256 + threadIdx.x;
  if (i >= n8) return;
  const float* p = in + (size_t)i * 8;
  f4 a = *(const f4*)p, b = *(const f4*)(p + 4);
  u16x8 o;
  #pragma unroll
  for (int j = 0; j < 4; ++j) { o[j] = f2bf(a[j]); o[4 + j] = f2bf(b[j]); }
  *(u16x8*)(out + (size_t)i * 8) = o;
}

__launch_bounds__(256)
__global__ void bias_k(const float* g1b, const float* g2b, float* b1, float* b2) {
  int i = blockIdx.x * 256 + threadIdx.x;
  if (i < 1024) { b1[i] = (i < 512) ? 0.f : -g1b[i - 512]; b2[i] = (i < 512) ? 0.f : -g2b[i - 512]; }
}

__launch_bounds__(256)
__global__ void rx_k(const u16* rz, const float* x, u16* rx) {
  int i = blockIdx.x * 256 + threadIdx.x;
  int m = i >> 6, d8 = (i & 63) << 3;
  u16x8 rv = *(const u16x8*)(rz + (size_t)m * 1024 + d8);
  const float* xp = x + (size_t)m * 512 + d8;
  f4 x0 = *(const f4*)xp, x1 = *(const f4*)(xp + 4);
  u16x8 o;
  #pragma unroll
  for (int j = 0; j < 4; ++j) { o[j] = f2bf(bf2f(rv[j]) * x0[j]); o[4 + j] = f2bf(bf2f(rv[4 + j]) * x1[j]); }
  *(u16x8*)(rx + (size_t)m * 512 + d8) = o;
}

__launch_bounds__(256)
__global__ void comb_k(const u16* rz, const u16* hg, const float* x, float* of, u16* ob) {
  int i = blockIdx.x * 256 + threadIdx.x;
  int m = i >> 6, d8 = (i & 63) << 3;
  u16x8 zv = *(const u16x8*)(rz + (size_t)m * 1024 + 512 + d8);
  u16x8 hv = *(const u16x8*)(hg + (size_t)m * 512 + d8);
  const float* xp = x + (size_t)m * 512 + d8;
  f4 x0 = *(const f4*)xp, x1 = *(const f4*)(xp + 4);
  f4 o0, o1; u16x8 obv;
  #pragma unroll
  for (int j = 0; j < 4; ++j) {
    float z = bf2f(zv[j]), hh = bf2f(hv[j]);
    float r = (1.f - z) * x0[j] + z * hh; o0[j] = r; obv[j] = f2bf(r);
  }
  #pragma unroll
  for (int j = 0; j < 4; ++j) {
    float z = bf2f(zv[4 + j]), hh = bf2f(hv[4 + j]);
    float r = (1.f - z) * x1[j] + z * hh; o1[j] = r; obv[4 + j] = f2bf(r);
  }
  float* op = of + (size_t)m * 512 + d8;
  *(f4*)op = o0; *(f4*)(op + 4) = o1;
  if (ob) *(u16x8*)(ob + (size_t)m * 512 + d8) = obv;
}

// ---------------- host ----------------
extern "C" void kernel_launch(void* const* d_in, const int* in_sizes, int n_in,
                              void* d_out, int out_size, void* d_ws, size_t ws_size,
                              hipStream_t stream) {
  const float* query = (const float*)d_in[0];
  const float* key   = (const float*)d_in[1];
  const float* pos   = (const float*)d_in[2];
  const float* U     = (const float*)d_in[3];
  const float* V     = (const float*)d_in[4];
  const float* attnW = (const float*)d_in[5];
  const float* ln1g  = (const float*)d_in[6];
  const float* ln1b  = (const float*)d_in[7];
  const float* ln2g  = (const float*)d_in[8];
  const float* ln2b  = (const float*)d_in[9];
  const float* g1W   = (const float*)d_in[10];
  const float* g1b   = (const float*)d_in[11];
  const float* g2W   = (const float*)d_in[12];
  const float* g2b   = (const float*)d_in[13];
  const float* fcW1  = (const float*)d_in[14];
  const float* fcb1  = (const float*)d_in[15];
  const float* fcW2  = (const float*)d_in[16];
  const float* fcb2  = (const float*)d_in[17];
  float* outp = (float*)d_out;

  char* base = (char*)d_ws;
  size_t off = 0;
  auto alloc = [&](size_t bytes) -> char* {
    char* p = base + off;
    off += (bytes + 255) & ~(size_t)255;
    return p;
  };

  u16* wT     = (u16*)alloc(17ull * 262144 * 2);
  u16* fc1T   = (u16*)alloc(2048ull * 512 * 2);
  u16* fc2T   = (u16*)alloc(2048ull * 512 * 2);
  u16* posb   = (u16*)alloc(1024ull * 512 * 2);
  u16* pbf    = (u16*)alloc(1024ull * 512 * 2);
  float* bias1 = (float*)alloc(1024 * 4);
  float* bias2 = (float*)alloc(1024 * 4);
  u16* nq     = (u16*)alloc(8192ull * 512 * 2);    // reused later as Y
  u16* nk     = (u16*)alloc(16384ull * 512 * 2);   // reused later as vT
  u16* xq     = (u16*)alloc(8192ull * 512 * 2);
  u16* qU     = (u16*)alloc(8192ull * 512 * 2);    // qU+qV reused later as out1 (fp32)
  u16* qV     = (u16*)alloc(8192ull * 512 * 2);
  u16* kv     = (u16*)alloc(16384ull * 1024 * 2);
  u16* y1     = (u16*)alloc(8192ull * 512 * 2);
  u16* ob1    = (u16*)alloc(8192ull * 512 * 2);
  u16* S      = (u16*)alloc(128ull * 524800 * 2 + 4096);  // flat-padded raw BD [B*H][512*1025]
  if (off > ws_size) return;

  // overlays
  u16* Y = nq;
  u16* vT = nk;
  float* out1f = (float*)qU;
  u16* rz1 = S;
  u16* rx1 = S + 8388608;
  u16* hg1 = rx1 + 4194304;
  u16* h2  = hg1 + 4194304;
  u16* e1  = h2 + 4194304;
  u16* y2  = e1 + 16777216;
  u16* rz2 = y2 + 4194304;
  u16* rx2 = rz2 + 8388608;
  u16* hg2 = rx2 + 4194304;

  // --- prep ---
  bias_k<<<dim3(4), dim3(256), 0, stream>>>(g1b, g2b, bias1, bias2);
  tsq_k<<<dim3(8, 8, 17), dim3(256), 0, stream>>>(attnW, g1W, g2W, wT);
  tgen_k<<<dim3(32, 8), dim3(256), 0, stream>>>(fcW1, fc1T, 512, 2048);
  tgen_k<<<dim3(8, 32), dim3(256), 0, stream>>>(fcW2, fc2T, 2048, 512);
  conv_k<<<dim3(256), dim3(256), 0, stream>>>(pos, posb, 65536);
  conv_k<<<dim3(2048), dim3(256), 0, stream>>>(query, xq, 524288);
  ln_k<<<dim3(2048), dim3(256), 0, stream>>>(query, ln1g, ln1b, nq);
  ln_k<<<dim3(4096), dim3(256), 0, stream>>>(key, ln1g, ln1b, nk);

  // --- projections ---
  { GemmP p{}; p.A = nq; p.B = wT; p.K1 = 512; p.lda = 512; p.ldb = 512; p.H = 1;
    p.C = qU; p.C2 = qV; p.ldc = 512; p.bias = U; p.bias2 = V;
    gemm_k<64,128,EPI_QUV,1><<<dim3(128,4,1), dim3(256), 0, stream>>>(p); }
  { GemmP p{}; p.A = nk; p.B = wT + 1ull*262144; p.K1 = 512; p.lda = 512; p.ldb = 512; p.H = 1;
    p.C = kv; p.ldc = 1024;
    gemm_k<128,128,EPI_BF16,0><<<dim3(128,8,1), dim3(256), 0, stream>>>(p); }
  { GemmP p{}; p.A = posb; p.B = wT + 3ull*262144; p.K1 = 512; p.lda = 512; p.ldb = 512; p.H = 1;
    p.C = pbf; p.ldc = 512;
    gemm_k<64,128,EPI_BF16,1><<<dim3(16,4,1), dim3(256), 0, stream>>>(p); }
  vtrans_k<<<dim3(16, 8, 16), dim3(256), 0, stream>>>(kv, vT);

  // --- raw BD into flat-padded buffer ---
  { GemmP p{}; p.A = qV; p.lda = 512; p.sAh = 64;
    p.B = pbf; p.ldb = 512; p.sBh = 64; p.K1 = 64; p.H = 8; p.S = S;
    gemm_k<128,128,EPI_BD,0><<<dim3(64,8,8), dim3(256), 0, stream>>>(p); }

  // --- fused attention: AC + BD + softmax + PV ---
  fattn_k<<<dim3(4, 128), dim3(256), 0, stream>>>(qU, kv, vT, S, Y);

  { GemmP p{}; p.A = Y; p.B = wT + 4ull*262144; p.K1 = 512; p.lda = 512; p.ldb = 512; p.H = 1;
    p.C = y1; p.ldc = 512;
    gemm_k<64,128,EPI_GELU,1><<<dim3(128,4,1), dim3(256), 0, stream>>>(p); }

  // --- gate 1 ---
  { GemmP p{}; p.A = y1; p.B = wT + 5ull*262144; p.K1 = 512;
    p.A2 = xq; p.B2 = wT + 7ull*262144; p.K2 = 512;
    p.lda = 512; p.ldb = 512; p.H = 1; p.C = rz1; p.ldc = 1024; p.bias = bias1;
    gemm_k<64,128,EPI_SIG,1><<<dim3(128,8,1), dim3(256), 0, stream>>>(p); }
  rx_k<<<dim3(2048), dim3(256), 0, stream>>>(rz1, query, rx1);
  { GemmP p{}; p.A = y1; p.B = wT + 9ull*262144; p.K1 = 512;
    p.A2 = rx1; p.B2 = wT + 10ull*262144; p.K2 = 512;
    p.lda = 512; p.ldb = 512; p.H = 1; p.C = hg1; p.ldc = 512;
    gemm_k<64,128,EPI_TANH,1><<<dim3(128,4,1), dim3(256), 0, stream>>>(p); }
  comb_k<<<dim3(2048), dim3(256), 0, stream>>>(rz1, hg1, query, out1f, ob1);

  // --- FFN ---
  ln_k<<<dim3(2048), dim3(256), 0, stream>>>(out1f, ln2g, ln2b, h2);
  { GemmP p{}; p.A = h2; p.B = fc1T; p.K1 = 512; p.lda = 512; p.ldb = 512; p.H = 1;
    p.C = e1; p.ldc = 2048; p.bias = fcb1;
    gemm_k<128,128,EPI_GELU,0><<<dim3(64,16,1), dim3(256), 0, stream>>>(p); }
  { GemmP p{}; p.A = e1; p.B = fc2T; p.K1 = 2048; p.lda = 2048; p.ldb = 2048; p.H = 1;
    p.C = y2; p.ldc = 512; p.bias = fcb2;
    gemm_k<64,128,EPI_GELU,1><<<dim3(128,4,1), dim3(256), 0, stream>>>(p); }

  // --- gate 2 ---
  { GemmP p{}; p.A = y2; p.B = wT + 11ull*262144; p.K1 = 512;
    p.A2 = ob1; p.B2 = wT + 13ull*262144; p.K2 = 512;
    p.lda = 512; p.ldb = 512; p.H = 1; p.C = rz2; p.ldc = 1024; p.bias = bias2;
    gemm_k<64,128,EPI_SIG,1><<<dim3(128,8,1), dim3(256), 0, stream>>>(p); }
  rx_k<<<dim3(2048), dim3(256), 0, stream>>>(rz2, out1f, rx2);
  { GemmP p{}; p.A = y2; p.B = wT + 15ull*262144; p.K1 = 512;
    p.A2 = rx2; p.B2 = wT + 16ull*262144; p.K2 = 512;
    p.lda = 512; p.ldb = 512; p.H = 1; p.C = hg2; p.ldc = 512;
    gemm_k<64,128,EPI_TANH,1><<<dim3(128,4,1), dim3(256), 0, stream>>>(p); }
  comb_k<<<dim3(2048), dim3(256), 0, stream>>>(rz2, hg2, out1f, outp, (u16*)nullptr);
}

// Round 9
// 435.811 us; speedup vs baseline: 1.1605x; 1.0282x over previous
//
#include <hip/hip_runtime.h>
#include <hip/hip_bf16.h>

typedef unsigned short u16;
typedef __attribute__((ext_vector_type(4))) float f4;
typedef __attribute__((ext_vector_type(8))) short s16x8;
typedef __attribute__((ext_vector_type(8))) unsigned short u16x8;
typedef __attribute__((ext_vector_type(4))) unsigned short u16x4;
typedef __attribute__((ext_vector_type(4))) int i32x4;
typedef __attribute__((ext_vector_type(2))) unsigned u32x2;

__device__ __forceinline__ u16 f2bf(float x){
  unsigned u = __float_as_uint(x);
  u += 0x7fffu + ((u >> 16) & 1u);
  return (u16)(u >> 16);
}
__device__ __forceinline__ float bf2f(u16 h){ return __uint_as_float(((unsigned)h) << 16); }

__device__ __forceinline__ unsigned cvt_pk_bf16(float lo, float hi){
  unsigned r;
  asm("v_cvt_pk_bf16_f32 %0, %1, %2" : "=v"(r) : "v"(lo), "v"(hi));
  return r;
}

__device__ __forceinline__ void gload_lds16(const u16* g, u16* l){
  __builtin_amdgcn_global_load_lds((__attribute__((address_space(1))) void*)g,
                                   (__attribute__((address_space(3))) void*)l, 16, 0, 0);
}

// ---------------- GEMM ----------------
// C[M,N] = A1[M,K1] @ B1t[N,K1]^T + A2[M,K2] @ B2t[N,K2]^T, bf16 in, fp32 acc.
struct GemmP {
  const u16* A; const u16* B;
  const u16* A2; const u16* B2;
  int K1, K2, lda, ldb, H;
  long long sAb, sAh, sBb, sBh;
  u16* C; long long sCb, sCh; int ldc;
  u16* C2;
  const float* bias; const float* bias2;
  u16* S;
};

enum { EPI_BF16=0, EPI_QUV=1, EPI_SIG=2, EPI_TANH=3, EPI_GELU=4, EPI_BD=5 };

// DB=1: 2-phase stage-early double-buffered pipeline (for small-grid / 1-2 blk/CU GEMMs)
template<int BM, int BN, int EPI, int DB>
__launch_bounds__(256)
__global__ void gemm_k(GemmP p) {
  constexpr int WN = (BN >= 128) ? 2 : 1;
  constexpr int WM = 4 / WN;
  constexpr int TM = BM / WM, TN = BN / WN;
  constexpr int FM = TM / 16, FN = TN / 16;
  constexpr int BUFE = (BM + BN) * 64;

  __shared__ __align__(16) u16 lds[BUFE * (DB ? 2 : 1)];

  const int tid = threadIdx.x;
  const int w = tid >> 6, lane = tid & 63;
  const int bz = blockIdx.z;
  const int b = bz / p.H, h = bz - b * p.H;
  const int m0 = blockIdx.x * BM, n0 = blockIdx.y * BN;

  const u16* Ab0 = p.A + (long long)b * p.sAb + (long long)h * p.sAh + (long long)m0 * p.lda;
  const u16* Bb0 = p.B + (long long)b * p.sBb + (long long)h * p.sBh + (long long)n0 * p.ldb;
  const u16* Ab1 = p.A2 ? p.A2 + (long long)m0 * p.lda : (const u16*)0;
  const u16* Bb1 = p.B2 ? p.B2 + (long long)n0 * p.ldb : (const u16*)0;

  f4 acc[FM][FN];
  #pragma unroll
  for (int i = 0; i < FM; ++i)
    #pragma unroll
    for (int j = 0; j < FN; ++j) acc[i][j] = f4{0.f, 0.f, 0.f, 0.f};

  const int s1 = p.K1 >> 6;
  const int st = s1 + (p.K2 >> 6);
  const int wM = w / WN, wN = w - wM * WN;

  auto stage = [&](int s, u16* lA_, u16* lB_) {
    const u16* Ab; const u16* Bb; int k0;
    if (s < s1) { Ab = Ab0; Bb = Bb0; k0 = s << 6; }
    else        { Ab = Ab1; Bb = Bb1; k0 = (s - s1) << 6; }
    #pragma unroll
    for (int i = 0; i < (BM >> 5); ++i) {
      int c = i * 256 + tid, row = c >> 3, cc = c & 7, sc = cc ^ (row & 7);
      gload_lds16(Ab + (long long)row * p.lda + k0 + sc * 8, lA_ + (size_t)(i * 4 + w) * 512);
    }
    #pragma unroll
    for (int i = 0; i < (BN >> 5); ++i) {
      int c = i * 256 + tid, row = c >> 3, cc = c & 7, sc = cc ^ (row & 7);
      gload_lds16(Bb + (long long)row * p.ldb + k0 + sc * 8, lB_ + (size_t)(i * 4 + w) * 512);
    }
  };

  auto compute = [&](const u16* lA_, const u16* lB_) {
    #pragma unroll
    for (int kk = 0; kk < 2; ++kk) {
      const int kb = lane >> 4;
      const int gc = kk * 4 + kb;
      s16x8 av[FM], bv[FN];
      #pragma unroll
      for (int fm = 0; fm < FM; ++fm) {
        int r = wM * TM + fm * 16 + (lane & 15);
        av[fm] = *(const s16x8*)(lA_ + r * 64 + ((gc ^ (r & 7)) << 3));
      }
      #pragma unroll
      for (int fn = 0; fn < FN; ++fn) {
        int r = wN * TN + fn * 16 + (lane & 15);
        bv[fn] = *(const s16x8*)(lB_ + r * 64 + ((gc ^ (r & 7)) << 3));
      }
      #pragma unroll
      for (int fm = 0; fm < FM; ++fm)
        #pragma unroll
        for (int fn = 0; fn < FN; ++fn)
          acc[fm][fn] = __builtin_amdgcn_mfma_f32_16x16x32_bf16(av[fm], bv[fn], acc[fm][fn], 0, 0, 0);
    }
  };

  if constexpr (DB) {
    stage(0, lds, lds + BM * 64);
    __syncthreads();
    for (int s = 0; s < st; ++s) {
      u16* cur = lds + (size_t)(s & 1) * BUFE;
      if (s + 1 < st) {
        u16* nxt = lds + (size_t)((s + 1) & 1) * BUFE;
        stage(s + 1, nxt, nxt + BM * 64);
      }
      compute(cur, cur + BM * 64);
      __syncthreads();   // drains staged loads (issued before compute) + read-safety
    }
  } else {
    for (int s = 0; s < st; ++s) {
      stage(s, lds, lds + BM * 64);
      __syncthreads();
      compute(lds, lds + BM * 64);
      __syncthreads();
    }
  }

  const int rb = (lane >> 4) << 2;
  const int cb = lane & 15;

  if constexpr (EPI == EPI_BD) {
    // raw BD (pre-scaled) into flat-padded buffer pitch 1025: idx = 1025q + 1 + t
    #pragma unroll
    for (int fm = 0; fm < FM; ++fm)
      #pragma unroll
      for (int fn = 0; fn < FN; ++fn)
        #pragma unroll
        for (int r = 0; r < 4; ++r) {
          int row = m0 + wM * TM + fm * 16 + rb + r;   // 0..8191 (b*512+q)
          int t   = n0 + wN * TN + fn * 16 + cb;
          int bb = row >> 9, q = row & 511;
          u16* Sp = p.S + (size_t)(bb * 8 + h) * 524800;
          Sp[(size_t)q * 1025 + 1 + t] = f2bf(acc[fm][fn][r] * 0.125f);
          if (t == 0 && q > 0) Sp[(size_t)q * 1025] = 0;  // rel-shift pad zero
        }
  } else if constexpr (EPI == EPI_QUV) {
    #pragma unroll
    for (int fm = 0; fm < FM; ++fm)
      #pragma unroll
      for (int fn = 0; fn < FN; ++fn)
        #pragma unroll
        for (int r = 0; r < 4; ++r) {
          int row = m0 + wM * TM + fm * 16 + rb + r;
          int col = n0 + wN * TN + fn * 16 + cb;
          size_t o = (size_t)row * p.ldc + col;
          float x = acc[fm][fn][r];
          p.C[o]  = f2bf(x + p.bias[col]);
          p.C2[o] = f2bf(x + p.bias2[col]);
        }
  } else {
    u16* Cb = p.C + (long long)b * p.sCb + (long long)h * p.sCh;
    #pragma unroll
    for (int fm = 0; fm < FM; ++fm)
      #pragma unroll
      for (int fn = 0; fn < FN; ++fn)
        #pragma unroll
        for (int r = 0; r < 4; ++r) {
          int row = m0 + wM * TM + fm * 16 + rb + r;
          int col = n0 + wN * TN + fn * 16 + cb;
          float x = acc[fm][fn][r];
          if (p.bias) x += p.bias[col];
          if constexpr (EPI == EPI_SIG)  x = 1.f / (1.f + __expf(-x));
          if constexpr (EPI == EPI_TANH) { float e = __expf(-2.f * fabsf(x)); float t = (1.f - e) / (1.f + e); x = copysignf(t, x); }
          if constexpr (EPI == EPI_GELU) x = 0.5f * x * (1.f + erff(x * 0.70710678118654752f));
          Cb[(size_t)row * p.ldc + col] = f2bf(x);
        }
  }
}

// ---------------- fused flash attention (swapped S^T layout, 8 waves, q-tile 128) ----------------
// grid (TQ/128, B*H), block 512. S^T = mfma(K,Q): lane owns q-column; softmax in-register;
// P packed via cvt_pk + ds_bpermute into PV B-operand; O^T = mfma(V^T, P^T); Y = O/l.
__launch_bounds__(512)
__global__ void fattn_k(const u16* __restrict__ qU, const u16* __restrict__ kv,
                        const u16* __restrict__ vT, const u16* __restrict__ BD,
                        u16* __restrict__ Y) {
  __shared__ __align__(16) u16 sBuf[2 * 16384];  // per buf: K[4096] V[4096] BD[8192]

  const int tid = threadIdx.x, w = tid >> 6, lane = tid & 63;
  const int q0 = blockIdx.x * 128;
  const int bz = blockIdx.y, b = bz >> 3, h = bz & 7;
  const int cq = lane & 15, kb = lane >> 4;
  const u16* Sb = BD + (size_t)bz * 524800;

  auto stage = [&](int j0, u16* buf) {
    u16* sK_ = buf; u16* sV_ = buf + 4096; u16* sB_ = buf + 8192;
    {
      int c = tid, row = c >> 3, cc = c & 7, sc = cc ^ (row & 7);
      gload_lds16(kv + ((size_t)(b * 1024 + j0 + row)) * 1024 + h * 64 + sc * 8,
                  sK_ + (size_t)w * 512);
      gload_lds16(vT + (size_t)bz * 65536 + (size_t)row * 1024 + j0 + sc * 8,
                  sV_ + (size_t)w * 512);
    }
    #pragma unroll
    for (int i = 0; i < 2; ++i) {
      int c = i * 512 + tid, row = c >> 3, cc = c & 7, sc = cc ^ (row & 7);
      gload_lds16(Sb + 512 + (size_t)(q0 + row) * 1024 + j0 + sc * 8,
                  sB_ + (size_t)(i * 8 + w) * 512);
    }
  };

  // Q B-fragments in registers (lane's q-row = q0 + w*16 + cq)
  const int qloc = w * 16 + cq;
  const u16* qrow = qU + ((size_t)(b * 512 + q0 + qloc)) * 512 + h * 64;
  s16x8 qb0 = *(const s16x8*)(qrow + kb * 8);
  s16x8 qb1 = *(const s16x8*)(qrow + 32 + kb * 8);

  stage(0, sBuf);
  __syncthreads();

  float m_s = -1e30f, l_s = 0.f;
  f4 O[4];
  #pragma unroll
  for (int fd = 0; fd < 4; ++fd) O[fd] = f4{0.f, 0.f, 0.f, 0.f};

  const int sw = qloc & 7;
  const int idxA = (cq + ((kb & 1) * 2) * 16) * 4;
  const int idxB = idxA + 64;

  for (int it = 0; it < 16; ++it) {
    u16* buf = sBuf + (size_t)(it & 1) * 16384;
    u16* sK_ = buf; u16* sV_ = buf + 4096; u16* sB_ = buf + 8192;
    if (it < 15) stage((it + 1) * 64, sBuf + (size_t)((it + 1) & 1) * 16384);

    // S^T = K @ Q^T : acc[fkv] holds S^T[kv=16fkv+kb*4+r][q=qloc]
    f4 acc[4];
    #pragma unroll
    for (int fkv = 0; fkv < 4; ++fkv) acc[fkv] = f4{0.f, 0.f, 0.f, 0.f};
    #pragma unroll
    for (int fkv = 0; fkv < 4; ++fkv) {
      int r = fkv * 16 + cq;
      s16x8 a0 = *(const s16x8*)(sK_ + r * 64 + ((kb ^ (r & 7)) << 3));
      s16x8 a1 = *(const s16x8*)(sK_ + r * 64 + (((4 + kb) ^ (r & 7)) << 3));
      acc[fkv] = __builtin_amdgcn_mfma_f32_16x16x32_bf16(a0, qb0, acc[fkv], 0, 0, 0);
      acc[fkv] = __builtin_amdgcn_mfma_f32_16x16x32_bf16(a1, qb1, acc[fkv], 0, 0, 0);
    }

    // scores + online softmax (lane-local q-column; reduce over kb groups only)
    float p[4][4];
    float tm = -1e30f;
    #pragma unroll
    for (int fkv = 0; fkv < 4; ++fkv) {
      int j8 = 2 * fkv + (kb >> 1);
      u16x4 bdv = *(const u16x4*)(sB_ + qloc * 64 + ((j8 ^ sw) << 3) + (kb & 1) * 4);
      #pragma unroll
      for (int r = 0; r < 4; ++r) {
        float s = acc[fkv][r] * 0.125f + bf2f(bdv[r]);
        p[fkv][r] = s;
        tm = fmaxf(tm, s);
      }
    }
    tm = fmaxf(tm, __shfl_xor(tm, 16));
    tm = fmaxf(tm, __shfl_xor(tm, 32));
    float mn = fmaxf(m_s, tm);
    float al = __expf(m_s - mn);
    m_s = mn;
    float ps = 0.f;
    #pragma unroll
    for (int fkv = 0; fkv < 4; ++fkv)
      #pragma unroll
      for (int r = 0; r < 4; ++r) { p[fkv][r] = __expf(p[fkv][r] - mn); ps += p[fkv][r]; }
    ps += __shfl_xor(ps, 16);
    ps += __shfl_xor(ps, 32);
    l_s = l_s * al + ps;
    #pragma unroll
    for (int fd = 0; fd < 4; ++fd)
      #pragma unroll
      for (int r = 0; r < 4; ++r) O[fd][r] *= al;

    // pack P^T to bf16 pairs, exchange into PV B-fragments
    unsigned W[4][2];
    #pragma unroll
    for (int fkv = 0; fkv < 4; ++fkv) {
      W[fkv][0] = cvt_pk_bf16(p[fkv][0], p[fkv][1]);
      W[fkv][1] = cvt_pk_bf16(p[fkv][2], p[fkv][3]);
    }
    s16x8 pb[2];
    #pragma unroll
    for (int c = 0; c < 2; ++c) {
      int a00 = __builtin_amdgcn_ds_bpermute(idxA, (int)W[2 * c][0]);
      int a01 = __builtin_amdgcn_ds_bpermute(idxA, (int)W[2 * c][1]);
      int a10 = __builtin_amdgcn_ds_bpermute(idxA, (int)W[2 * c + 1][0]);
      int a11 = __builtin_amdgcn_ds_bpermute(idxA, (int)W[2 * c + 1][1]);
      int b00 = __builtin_amdgcn_ds_bpermute(idxB, (int)W[2 * c][0]);
      int b01 = __builtin_amdgcn_ds_bpermute(idxB, (int)W[2 * c][1]);
      int b10 = __builtin_amdgcn_ds_bpermute(idxB, (int)W[2 * c + 1][0]);
      int b11 = __builtin_amdgcn_ds_bpermute(idxB, (int)W[2 * c + 1][1]);
      bool hi = (kb >= 2);
      i32x4 t;
      t[0] = hi ? a10 : a00;
      t[1] = hi ? a11 : a01;
      t[2] = hi ? b10 : b00;
      t[3] = hi ? b11 : b01;
      pb[c] = *(s16x8*)&t;
    }

    // PV: O^T[d][q] += V^T @ P^T
    #pragma unroll
    for (int c = 0; c < 2; ++c)
      #pragma unroll
      for (int fd = 0; fd < 4; ++fd) {
        int rd = fd * 16 + cq;
        s16x8 vb = *(const s16x8*)(sV_ + rd * 64 + (((c * 4 + kb) ^ (rd & 7)) << 3));
        O[fd] = __builtin_amdgcn_mfma_f32_16x16x32_bf16(vb, pb[c], O[fd], 0, 0, 0);
      }
    __syncthreads();   // drains next-tile loads + read-safety for buffer reuse
  }

  // normalize + packed write: Y[(b*512+q)*512 + h*64 + d], 4 consecutive d per store
  float invl = 1.f / l_s;
  u16* yrow = Y + ((size_t)(b * 512 + q0 + qloc)) * 512 + h * 64;
  #pragma unroll
  for (int fd = 0; fd < 4; ++fd) {
    unsigned w0 = cvt_pk_bf16(O[fd][0] * invl, O[fd][1] * invl);
    unsigned w1 = cvt_pk_bf16(O[fd][2] * invl, O[fd][3] * invl);
    u32x2 st; st[0] = w0; st[1] = w1;
    *(u32x2*)(yrow + fd * 16 + kb * 4) = st;
  }
}

// ---------------- LayerNorm (D=512), fp32 in -> bf16 out ----------------
__launch_bounds__(256)
__global__ void ln_k(const float* __restrict__ x, const float* __restrict__ g,
                     const float* __restrict__ be, u16* __restrict__ out) {
  int row  = blockIdx.x * 4 + (threadIdx.x >> 6);
  int lane = threadIdx.x & 63;
  const float* xr = x + (size_t)row * 512 + lane * 8;
  f4 v0 = *(const f4*)xr;
  f4 v1 = *(const f4*)(xr + 4);
  float s = 0.f, q = 0.f;
  #pragma unroll
  for (int i = 0; i < 4; ++i) { s += v0[i] + v1[i]; q += v0[i]*v0[i] + v1[i]*v1[i]; }
  #pragma unroll
  for (int o = 32; o > 0; o >>= 1) { s += __shfl_xor(s, o); q += __shfl_xor(q, o); }
  float mu = s * (1.f / 512.f);
  float rs = rsqrtf(q * (1.f / 512.f) - mu * mu + 1e-5f);
  int c = lane * 8;
  u16x8 o;
  #pragma unroll
  for (int i = 0; i < 8; ++i) {
    float xx = (i < 4) ? v0[i] : v1[i - 4];
    o[i] = f2bf((xx - mu) * rs * g[c + i] + be[c + i]);
  }
  *(u16x8*)(out + (size_t)row * 512 + c) = o;
}

// ---------------- transpose helpers: src fp32 [R][C] -> dst bf16 [C][R] ----------------
__device__ __forceinline__ void tbody(float (*t)[65], const float* src, u16* dst,
                                      int R, int C, int bx, int by, int tid) {
  int c0 = bx * 64, r0 = by * 64;
  #pragma unroll
  for (int i = 0; i < 4; ++i) {
    int r = i * 16 + (tid >> 4);
    int c4 = (tid & 15) * 4;
    f4 v = *(const f4*)(src + (size_t)(r0 + r) * C + c0 + c4);
    t[r][c4] = v.x; t[r][c4 + 1] = v.y; t[r][c4 + 2] = v.z; t[r][c4 + 3] = v.w;
  }
  __syncthreads();
  #pragma unroll
  for (int i = 0; i < 2; ++i) {
    int id = i * 256 + tid;
    int rr = id >> 3, c8 = (id & 7) * 8;
    u16x8 o;
    #pragma unroll
    for (int j = 0; j < 8; ++j) o[j] = f2bf(t[c8 + j][rr]);
    *(u16x8*)(dst + (size_t)(c0 + rr) * R + r0 + c8) = o;
  }
}

__launch_bounds__(256)
__global__ void tsq_k(const float* aW, const float* g1W, const float* g2W, u16* wT) {
  __shared__ float t[64][65];
  int z = blockIdx.z;
  const int lut[6] = {0, 2, 1, 3, 4, 5};
  const float* src; u16* dst;
  if (z < 5)       { src = aW  + (size_t)z * 262144;        dst = wT + (size_t)z * 262144; }
  else if (z < 11) { int j = z - 5;  src = g1W + (size_t)j * 262144; dst = wT + (size_t)(5 + lut[j]) * 262144; }
  else             { int j = z - 11; src = g2W + (size_t)j * 262144; dst = wT + (size_t)(11 + lut[j]) * 262144; }
  tbody(t, src, dst, 512, 512, blockIdx.x, blockIdx.y, threadIdx.x);
}

__launch_bounds__(256)
__global__ void tgen_k(const float* src, u16* dst, int R, int C) {
  __shared__ float t[64][65];
  tbody(t, src, dst, R, C, blockIdx.x, blockIdx.y, threadIdx.x);
}

// ---------------- v transpose: kv cols 512.. -> vT[b,h][64][1024] ----------------
__launch_bounds__(256)
__global__ void vtrans_k(const u16* kv, u16* vT) {
  int jt = blockIdx.x, h = blockIdx.y, b = blockIdx.z;
  __shared__ u16 t[64][72];
  int tid = threadIdx.x;
  const u16* src = kv + ((size_t)b * 1024 + jt * 64) * 1024 + 512 + h * 64;
  #pragma unroll
  for (int i = 0; i < 2; ++i) {
    int id = i * 256 + tid;
    int r = id >> 3, c = (id & 7) * 8;
    u16x8 v = *(const u16x8*)(src + (size_t)r * 1024 + c);
    #pragma unroll
    for (int j = 0; j < 8; ++j) t[r][c + j] = v[j];
  }
  __syncthreads();
  u16* dst = vT + (size_t)(b * 8 + h) * 65536 + (size_t)jt * 64;
  #pragma unroll
  for (int i = 0; i < 2; ++i) {
    int id = i * 256 + tid;
    int d = id >> 3, c = (id & 7) * 8;
    u16x8 o;
    #pragma unroll
    for (int j = 0; j < 8; ++j) o[j] = t[c + j][d];
    *(u16x8*)(dst + (size_t)d * 1024 + c) = o;
  }
}

// ---------------- small elementwise ----------------
__launch_bounds__(256)
__global__ void conv_k(const float* in, u16* out, int n8) {
  int i = blockIdx.x * 256 + threadIdx.x;
  if (i >= n8) return;
  const float* p = in + (size_t)i * 8;
  f4 a = *(const f4*)p, b = *(const f4*)(p + 4);
  u16x8 o;
  #pragma unroll
  for (int j = 0; j < 4; ++j) { o[j] = f2bf(a[j]); o[4 + j] = f2bf(b[j]); }
  *(u16x8*)(out + (size_t)i * 8) = o;
}

__launch_bounds__(256)
__global__ void bias_k(const float* g1b, const float* g2b, float* b1, float* b2) {
  int i = blockIdx.x * 256 + threadIdx.x;
  if (i < 1024) { b1[i] = (i < 512) ? 0.f : -g1b[i - 512]; b2[i] = (i < 512) ? 0.f : -g2b[i - 512]; }
}

__launch_bounds__(256)
__global__ void rx_k(const u16* rz, const float* x, u16* rx) {
  int i = blockIdx.x * 256 + threadIdx.x;
  int m = i >> 6, d8 = (i & 63) << 3;
  u16x8 rv = *(const u16x8*)(rz + (size_t)m * 1024 + d8);
  const float* xp = x + (size_t)m * 512 + d8;
  f4 x0 = *(const f4*)xp, x1 = *(const f4*)(xp + 4);
  u16x8 o;
  #pragma unroll
  for (int j = 0; j < 4; ++j) { o[j] = f2bf(bf2f(rv[j]) * x0[j]); o[4 + j] = f2bf(bf2f(rv[4 + j]) * x1[j]); }
  *(u16x8*)(rx + (size_t)m * 512 + d8) = o;
}

__launch_bounds__(256)
__global__ void comb_k(const u16* rz, const u16* hg, const float* x, float* of, u16* ob) {
  int i = blockIdx.x * 256 + threadIdx.x;
  int m = i >> 6, d8 = (i & 63) << 3;
  u16x8 zv = *(const u16x8*)(rz + (size_t)m * 1024 + 512 + d8);
  u16x8 hv = *(const u16x8*)(hg + (size_t)m * 512 + d8);
  const float* xp = x + (size_t)m * 512 + d8;
  f4 x0 = *(const f4*)xp, x1 = *(const f4*)(xp + 4);
  f4 o0, o1; u16x8 obv;
  #pragma unroll
  for (int j = 0; j < 4; ++j) {
    float z = bf2f(zv[j]), hh = bf2f(hv[j]);
    float r = (1.f - z) * x0[j] + z * hh; o0[j] = r; obv[j] = f2bf(r);
  }
  #pragma unroll
  for (int j = 0; j < 4; ++j) {
    float z = bf2f(zv[4 + j]), hh = bf2f(hv[4 + j]);
    float r = (1.f - z) * x1[j] + z * hh; o1[j] = r; obv[4 + j] = f2bf(r);
  }
  float* op = of + (size_t)m * 512 + d8;
  *(f4*)op = o0; *(f4*)(op + 4) = o1;
  if (ob) *(u16x8*)(ob + (size_t)m * 512 + d8) = obv;
}

// ---------------- host ----------------
extern "C" void kernel_launch(void* const* d_in, const int* in_sizes, int n_in,
                              void* d_out, int out_size, void* d_ws, size_t ws_size,
                              hipStream_t stream) {
  const float* query = (const float*)d_in[0];
  const float* key   = (const float*)d_in[1];
  const float* pos   = (const float*)d_in[2];
  const float* U     = (const float*)d_in[3];
  const float* V     = (const float*)d_in[4];
  const float* attnW = (const float*)d_in[5];
  const float* ln1g  = (const float*)d_in[6];
  const float* ln1b  = (const float*)d_in[7];
  const float* ln2g  = (const float*)d_in[8];
  const float* ln2b  = (const float*)d_in[9];
  const float* g1W   = (const float*)d_in[10];
  const float* g1b   = (const float*)d_in[11];
  const float* g2W   = (const float*)d_in[12];
  const float* g2b   = (const float*)d_in[13];
  const float* fcW1  = (const float*)d_in[14];
  const float* fcb1  = (const float*)d_in[15];
  const float* fcW2  = (const float*)d_in[16];
  const float* fcb2  = (const float*)d_in[17];
  float* outp = (float*)d_out;

  char* base = (char*)d_ws;
  size_t off = 0;
  auto alloc = [&](size_t bytes) -> char* {
    char* p = base + off;
    off += (bytes + 255) & ~(size_t)255;
    return p;
  };

  u16* wT     = (u16*)alloc(17ull * 262144 * 2);
  u16* fc1T   = (u16*)alloc(2048ull * 512 * 2);
  u16* fc2T   = (u16*)alloc(2048ull * 512 * 2);
  u16* posb   = (u16*)alloc(1024ull * 512 * 2);
  u16* pbf    = (u16*)alloc(1024ull * 512 * 2);
  float* bias1 = (float*)alloc(1024 * 4);
  float* bias2 = (float*)alloc(1024 * 4);
  u16* nq     = (u16*)alloc(8192ull * 512 * 2);    // reused later as Y
  u16* nk     = (u16*)alloc(16384ull * 512 * 2);   // reused later as vT
  u16* xq     = (u16*)alloc(8192ull * 512 * 2);
  u16* qU     = (u16*)alloc(8192ull * 512 * 2);    // qU+qV reused later as out1 (fp32)
  u16* qV     = (u16*)alloc(8192ull * 512 * 2);
  u16* kv     = (u16*)alloc(16384ull * 1024 * 2);
  u16* y1     = (u16*)alloc(8192ull * 512 * 2);
  u16* ob1    = (u16*)alloc(8192ull * 512 * 2);
  u16* S      = (u16*)alloc(128ull * 524800 * 2 + 4096);  // flat-padded raw BD [B*H][512*1025]
  if (off > ws_size) return;

  // overlays
  u16* Y = nq;
  u16* vT = nk;
  float* out1f = (float*)qU;
  u16* rz1 = S;
  u16* rx1 = S + 8388608;
  u16* hg1 = rx1 + 4194304;
  u16* h2  = hg1 + 4194304;
  u16* e1  = h2 + 4194304;
  u16* y2  = e1 + 16777216;
  u16* rz2 = y2 + 4194304;
  u16* rx2 = rz2 + 8388608;
  u16* hg2 = rx2 + 4194304;

  // --- prep ---
  bias_k<<<dim3(4), dim3(256), 0, stream>>>(g1b, g2b, bias1, bias2);
  tsq_k<<<dim3(8, 8, 17), dim3(256), 0, stream>>>(attnW, g1W, g2W, wT);
  tgen_k<<<dim3(32, 8), dim3(256), 0, stream>>>(fcW1, fc1T, 512, 2048);
  tgen_k<<<dim3(8, 32), dim3(256), 0, stream>>>(fcW2, fc2T, 2048, 512);
  conv_k<<<dim3(256), dim3(256), 0, stream>>>(pos, posb, 65536);
  conv_k<<<dim3(2048), dim3(256), 0, stream>>>(query, xq, 524288);
  ln_k<<<dim3(2048), dim3(256), 0, stream>>>(query, ln1g, ln1b, nq);
  ln_k<<<dim3(4096), dim3(256), 0, stream>>>(key, ln1g, ln1b, nk);

  // --- projections ---
  { GemmP p{}; p.A = nq; p.B = wT; p.K1 = 512; p.lda = 512; p.ldb = 512; p.H = 1;
    p.C = qU; p.C2 = qV; p.ldc = 512; p.bias = U; p.bias2 = V;
    gemm_k<64,128,EPI_QUV,1><<<dim3(128,4,1), dim3(256), 0, stream>>>(p); }
  { GemmP p{}; p.A = nk; p.B = wT + 1ull*262144; p.K1 = 512; p.lda = 512; p.ldb = 512; p.H = 1;
    p.C = kv; p.ldc = 1024;
    gemm_k<128,128,EPI_BF16,0><<<dim3(128,8,1), dim3(256), 0, stream>>>(p); }
  { GemmP p{}; p.A = posb; p.B = wT + 3ull*262144; p.K1 = 512; p.lda = 512; p.ldb = 512; p.H = 1;
    p.C = pbf; p.ldc = 512;
    gemm_k<64,128,EPI_BF16,1><<<dim3(16,4,1), dim3(256), 0, stream>>>(p); }
  vtrans_k<<<dim3(16, 8, 16), dim3(256), 0, stream>>>(kv, vT);

  // --- raw BD into flat-padded buffer ---
  { GemmP p{}; p.A = qV; p.lda = 512; p.sAh = 64;
    p.B = pbf; p.ldb = 512; p.sBh = 64; p.K1 = 64; p.H = 8; p.S = S;
    gemm_k<128,128,EPI_BD,0><<<dim3(64,8,8), dim3(256), 0, stream>>>(p); }

  // --- fused attention: AC + BD + softmax + PV ---
  fattn_k<<<dim3(4, 128), dim3(512), 0, stream>>>(qU, kv, vT, S, Y);

  { GemmP p{}; p.A = Y; p.B = wT + 4ull*262144; p.K1 = 512; p.lda = 512; p.ldb = 512; p.H = 1;
    p.C = y1; p.ldc = 512;
    gemm_k<64,128,EPI_GELU,1><<<dim3(128,4,1), dim3(256), 0, stream>>>(p); }

  // --- gate 1 ---
  { GemmP p{}; p.A = y1; p.B = wT + 5ull*262144; p.K1 = 512;
    p.A2 = xq; p.B2 = wT + 7ull*262144; p.K2 = 512;
    p.lda = 512; p.ldb = 512; p.H = 1; p.C = rz1; p.ldc = 1024; p.bias = bias1;
    gemm_k<64,128,EPI_SIG,1><<<dim3(128,8,1), dim3(256), 0, stream>>>(p); }
  rx_k<<<dim3(2048), dim3(256), 0, stream>>>(rz1, query, rx1);
  { GemmP p{}; p.A = y1; p.B = wT + 9ull*262144; p.K1 = 512;
    p.A2 = rx1; p.B2 = wT + 10ull*262144; p.K2 = 512;
    p.lda = 512; p.ldb = 512; p.H = 1; p.C = hg1; p.ldc = 512;
    gemm_k<64,128,EPI_TANH,1><<<dim3(128,4,1), dim3(256), 0, stream>>>(p); }
  comb_k<<<dim3(2048), dim3(256), 0, stream>>>(rz1, hg1, query, out1f, ob1);

  // --- FFN ---
  ln_k<<<dim3(2048), dim3(256), 0, stream>>>(out1f, ln2g, ln2b, h2);
  { GemmP p{}; p.A = h2; p.B = fc1T; p.K1 = 512; p.lda = 512; p.ldb = 512; p.H = 1;
    p.C = e1; p.ldc = 2048; p.bias = fcb1;
    gemm_k<128,128,EPI_GELU,0><<<dim3(64,16,1), dim3(256), 0, stream>>>(p); }
  { GemmP p{}; p.A = e1; p.B = fc2T; p.K1 = 2048; p.lda = 2048; p.ldb = 2048; p.H = 1;
    p.C = y2; p.ldc = 512; p.bias = fcb2;
    gemm_k<64,128,EPI_GELU,1><<<dim3(128,4,1), dim3(256), 0, stream>>>(p); }

  // --- gate 2 ---
  { GemmP p{}; p.A = y2; p.B = wT + 11ull*262144; p.K1 = 512;
    p.A2 = ob1; p.B2 = wT + 13ull*262144; p.K2 = 512;
    p.lda = 512; p.ldb = 512; p.H = 1; p.C = rz2; p.ldc = 1024; p.bias = bias2;
    gemm_k<64,128,EPI_SIG,1><<<dim3(128,8,1), dim3(256), 0, stream>>>(p); }
  rx_k<<<dim3(2048), dim3(256), 0, stream>>>(rz2, out1f, rx2);
  { GemmP p{}; p.A = y2; p.B = wT + 15ull*262144; p.K1 = 512;
    p.A2 = rx2; p.B2 = wT + 16ull*262144; p.K2 = 512;
    p.lda = 512; p.ldb = 512; p.H = 1; p.C = hg2; p.ldc = 512;
    gemm_k<64,128,EPI_TANH,1><<<dim3(128,4,1), dim3(256), 0, stream>>>(p); }
  comb_k<<<dim3(2048), dim3(256), 0, stream>>>(rz2, hg2, out1f, outp, (u16*)nullptr);
}

// Round 10
// 400.298 us; speedup vs baseline: 1.2635x; 1.0887x over previous
//
#include <hip/hip_runtime.h>
#include <hip/hip_bf16.h>

typedef unsigned short u16;
typedef __attribute__((ext_vector_type(4))) float f4;
typedef __attribute__((ext_vector_type(8))) short s16x8;
typedef __attribute__((ext_vector_type(8))) unsigned short u16x8;
typedef __attribute__((ext_vector_type(4))) unsigned short u16x4;
typedef __attribute__((ext_vector_type(4))) int i32x4;
typedef __attribute__((ext_vector_type(2))) unsigned u32x2;

__device__ __forceinline__ u16 f2bf(float x){
  unsigned u = __float_as_uint(x);
  u += 0x7fffu + ((u >> 16) & 1u);
  return (u16)(u >> 16);
}
__device__ __forceinline__ float bf2f(u16 h){ return __uint_as_float(((unsigned)h) << 16); }

__device__ __forceinline__ unsigned cvt_pk_bf16(float lo, float hi){
  unsigned r;
  asm("v_cvt_pk_bf16_f32 %0, %1, %2" : "=v"(r) : "v"(lo), "v"(hi));
  return r;
}

__device__ __forceinline__ void gload_lds16(const u16* g, u16* l){
  __builtin_amdgcn_global_load_lds((__attribute__((address_space(1))) void*)g,
                                   (__attribute__((address_space(3))) void*)l, 16, 0, 0);
}

// fast activations (bf16-output tolerance): tanh-form GELU (|err| <= ~1e-3 abs), rcp-based sig/tanh
__device__ __forceinline__ float gelu_f(float x){
  float u = x * (0.7978845608f + 0.0356774081f * x * x);   // 0.79788456*(x+0.044715x^3)
  float e = __expf(-2.f * u);
  return x * __builtin_amdgcn_rcpf(1.f + e);               // 0.5x(1+tanh(u)) = x/(1+e^-2u)
}
__device__ __forceinline__ float sig_f(float x){
  float e = __expf(-x);
  return __builtin_amdgcn_rcpf(1.f + e);
}
__device__ __forceinline__ float tanh_f(float x){
  float e = __expf(-2.f * fabsf(x));
  float t = (1.f - e) * __builtin_amdgcn_rcpf(1.f + e);
  return copysignf(t, x);
}

// ---------------- GEMM ----------------
// C[M,N] = A1[M,K1] @ B1t[N,K1]^T + A2[M,K2] @ B2t[N,K2]^T, bf16 in, fp32 acc.
struct GemmP {
  const u16* A; const u16* B;
  const u16* A2; const u16* B2;
  int K1, K2, lda, ldb, H;
  long long sAb, sAh, sBb, sBh;
  u16* C; long long sCb, sCh; int ldc;
  u16* C2;
  const float* bias; const float* bias2;
  u16* S;
};

enum { EPI_BF16=0, EPI_QUV=1, EPI_SIG=2, EPI_TANH=3, EPI_GELU=4, EPI_BD=5 };

// DB=1: 2-phase stage-early double-buffered pipeline (for small-grid / 1-2 blk/CU GEMMs)
template<int BM, int BN, int EPI, int DB>
__launch_bounds__(256)
__global__ void gemm_k(GemmP p) {
  constexpr int WN = (BN >= 128) ? 2 : 1;
  constexpr int WM = 4 / WN;
  constexpr int TM = BM / WM, TN = BN / WN;
  constexpr int FM = TM / 16, FN = TN / 16;
  constexpr int BUFE = (BM + BN) * 64;

  __shared__ __align__(16) u16 lds[BUFE * (DB ? 2 : 1)];

  const int tid = threadIdx.x;
  const int w = tid >> 6, lane = tid & 63;
  const int bz = blockIdx.z;
  const int b = bz / p.H, h = bz - b * p.H;
  const int m0 = blockIdx.x * BM, n0 = blockIdx.y * BN;

  const u16* Ab0 = p.A + (long long)b * p.sAb + (long long)h * p.sAh + (long long)m0 * p.lda;
  const u16* Bb0 = p.B + (long long)b * p.sBb + (long long)h * p.sBh + (long long)n0 * p.ldb;
  const u16* Ab1 = p.A2 ? p.A2 + (long long)m0 * p.lda : (const u16*)0;
  const u16* Bb1 = p.B2 ? p.B2 + (long long)n0 * p.ldb : (const u16*)0;

  f4 acc[FM][FN];
  #pragma unroll
  for (int i = 0; i < FM; ++i)
    #pragma unroll
    for (int j = 0; j < FN; ++j) acc[i][j] = f4{0.f, 0.f, 0.f, 0.f};

  const int s1 = p.K1 >> 6;
  const int st = s1 + (p.K2 >> 6);
  const int wM = w / WN, wN = w - wM * WN;

  // hoisted per-thread staging offsets (swizzle row&7 is invariant across 32-row chunks)
  const int srow = tid >> 3;
  const long long sc8 = (long long)(((tid & 7) ^ (srow & 7)) << 3);
  const long long aoff = (long long)srow * p.lda + sc8;
  const long long boff = (long long)srow * p.ldb + sc8;

  auto stage = [&](int s, u16* lA_, u16* lB_) {
    const u16* Ab; const u16* Bb; int k0;
    if (s < s1) { Ab = Ab0; Bb = Bb0; k0 = s << 6; }
    else        { Ab = Ab1; Bb = Bb1; k0 = (s - s1) << 6; }
    const u16* pa = Ab + aoff + k0;
    const u16* pb = Bb + boff + k0;
    #pragma unroll
    for (int i = 0; i < (BM >> 5); ++i)
      gload_lds16(pa + (long long)(i * 32) * p.lda, lA_ + (size_t)(i * 4 + w) * 512);
    #pragma unroll
    for (int i = 0; i < (BN >> 5); ++i)
      gload_lds16(pb + (long long)(i * 32) * p.ldb, lB_ + (size_t)(i * 4 + w) * 512);
  };

  auto compute = [&](const u16* lA_, const u16* lB_) {
    #pragma unroll
    for (int kk = 0; kk < 2; ++kk) {
      const int kb = lane >> 4;
      const int gc = kk * 4 + kb;
      s16x8 av[FM], bv[FN];
      #pragma unroll
      for (int fm = 0; fm < FM; ++fm) {
        int r = wM * TM + fm * 16 + (lane & 15);
        av[fm] = *(const s16x8*)(lA_ + r * 64 + ((gc ^ (r & 7)) << 3));
      }
      #pragma unroll
      for (int fn = 0; fn < FN; ++fn) {
        int r = wN * TN + fn * 16 + (lane & 15);
        bv[fn] = *(const s16x8*)(lB_ + r * 64 + ((gc ^ (r & 7)) << 3));
      }
      #pragma unroll
      for (int fm = 0; fm < FM; ++fm)
        #pragma unroll
        for (int fn = 0; fn < FN; ++fn)
          acc[fm][fn] = __builtin_amdgcn_mfma_f32_16x16x32_bf16(av[fm], bv[fn], acc[fm][fn], 0, 0, 0);
    }
  };

  if constexpr (DB) {
    stage(0, lds, lds + BM * 64);
    __syncthreads();
    for (int s = 0; s < st; ++s) {
      u16* cur = lds + (size_t)(s & 1) * BUFE;
      if (s + 1 < st) {
        u16* nxt = lds + (size_t)((s + 1) & 1) * BUFE;
        stage(s + 1, nxt, nxt + BM * 64);
      }
      compute(cur, cur + BM * 64);
      __syncthreads();   // drains staged loads (issued before compute) + read-safety
    }
  } else {
    for (int s = 0; s < st; ++s) {
      stage(s, lds, lds + BM * 64);
      __syncthreads();
      compute(lds, lds + BM * 64);
      __syncthreads();
    }
  }

  const int rb = (lane >> 4) << 2;
  const int cb = lane & 15;

  if constexpr (EPI == EPI_BD) {
    // raw BD (pre-scaled) into flat-padded buffer pitch 1025: idx = 1025q + 1 + t
    #pragma unroll
    for (int fm = 0; fm < FM; ++fm)
      #pragma unroll
      for (int fn = 0; fn < FN; ++fn)
        #pragma unroll
        for (int r = 0; r < 4; ++r) {
          int row = m0 + wM * TM + fm * 16 + rb + r;   // 0..8191 (b*512+q)
          int t   = n0 + wN * TN + fn * 16 + cb;
          int bb = row >> 9, q = row & 511;
          u16* Sp = p.S + (size_t)(bb * 8 + h) * 524800;
          Sp[(size_t)q * 1025 + 1 + t] = f2bf(acc[fm][fn][r] * 0.125f);
          if (t == 0 && q > 0) Sp[(size_t)q * 1025] = 0;  // rel-shift pad zero
        }
  } else if constexpr (EPI == EPI_QUV) {
    #pragma unroll
    for (int fm = 0; fm < FM; ++fm)
      #pragma unroll
      for (int fn = 0; fn < FN; ++fn)
        #pragma unroll
        for (int r = 0; r < 4; ++r) {
          int row = m0 + wM * TM + fm * 16 + rb + r;
          int col = n0 + wN * TN + fn * 16 + cb;
          size_t o = (size_t)row * p.ldc + col;
          float x = acc[fm][fn][r];
          p.C[o]  = f2bf(x + p.bias[col]);
          p.C2[o] = f2bf(x + p.bias2[col]);
        }
  } else {
    u16* Cb = p.C + (long long)b * p.sCb + (long long)h * p.sCh;
    #pragma unroll
    for (int fm = 0; fm < FM; ++fm)
      #pragma unroll
      for (int fn = 0; fn < FN; ++fn)
        #pragma unroll
        for (int r = 0; r < 4; ++r) {
          int row = m0 + wM * TM + fm * 16 + rb + r;
          int col = n0 + wN * TN + fn * 16 + cb;
          float x = acc[fm][fn][r];
          if (p.bias) x += p.bias[col];
          if constexpr (EPI == EPI_SIG)  x = sig_f(x);
          if constexpr (EPI == EPI_TANH) x = tanh_f(x);
          if constexpr (EPI == EPI_GELU) x = gelu_f(x);
          Cb[(size_t)row * p.ldc + col] = f2bf(x);
        }
  }
}

// ---------------- fused flash attention (swapped S^T layout, 8 waves, q-tile 128) ----------------
// grid (TQ/128, B*H), block 512. S^T = mfma(K,Q): lane owns q-column; softmax in-register;
// P packed via cvt_pk + ds_bpermute into PV B-operand; O^T = mfma(V^T, P^T); Y = O/l.
__launch_bounds__(512)
__global__ void fattn_k(const u16* __restrict__ qU, const u16* __restrict__ kv,
                        const u16* __restrict__ vT, const u16* __restrict__ BD,
                        u16* __restrict__ Y) {
  __shared__ __align__(16) u16 sBuf[2 * 16384];  // per buf: K[4096] V[4096] BD[8192]

  const int tid = threadIdx.x, w = tid >> 6, lane = tid & 63;
  const int q0 = blockIdx.x * 128;
  const int bz = blockIdx.y, b = bz >> 3, h = bz & 7;
  const int cq = lane & 15, kb = lane >> 4;
  const u16* Sb = BD + (size_t)bz * 524800;

  auto stage = [&](int j0, u16* buf) {
    u16* sK_ = buf; u16* sV_ = buf + 4096; u16* sB_ = buf + 8192;
    {
      int c = tid, row = c >> 3, cc = c & 7, sc = cc ^ (row & 7);
      gload_lds16(kv + ((size_t)(b * 1024 + j0 + row)) * 1024 + h * 64 + sc * 8,
                  sK_ + (size_t)w * 512);
      gload_lds16(vT + (size_t)bz * 65536 + (size_t)row * 1024 + j0 + sc * 8,
                  sV_ + (size_t)w * 512);
    }
    #pragma unroll
    for (int i = 0; i < 2; ++i) {
      int c = i * 512 + tid, row = c >> 3, cc = c & 7, sc = cc ^ (row & 7);
      gload_lds16(Sb + 512 + (size_t)(q0 + row) * 1024 + j0 + sc * 8,
                  sB_ + (size_t)(i * 8 + w) * 512);
    }
  };

  // Q B-fragments in registers (lane's q-row = q0 + w*16 + cq)
  const int qloc = w * 16 + cq;
  const u16* qrow = qU + ((size_t)(b * 512 + q0 + qloc)) * 512 + h * 64;
  s16x8 qb0 = *(const s16x8*)(qrow + kb * 8);
  s16x8 qb1 = *(const s16x8*)(qrow + 32 + kb * 8);

  stage(0, sBuf);
  __syncthreads();

  float m_s = -1e30f, l_s = 0.f;
  f4 O[4];
  #pragma unroll
  for (int fd = 0; fd < 4; ++fd) O[fd] = f4{0.f, 0.f, 0.f, 0.f};

  const int sw = qloc & 7;
  const int idxA = (cq + ((kb & 1) * 2) * 16) * 4;
  const int idxB = idxA + 64;

  for (int it = 0; it < 16; ++it) {
    u16* buf = sBuf + (size_t)(it & 1) * 16384;
    u16* sK_ = buf; u16* sV_ = buf + 4096; u16* sB_ = buf + 8192;
    if (it < 15) stage((it + 1) * 64, sBuf + (size_t)((it + 1) & 1) * 16384);

    // S^T = K @ Q^T : acc[fkv] holds S^T[kv=16fkv+kb*4+r][q=qloc]
    f4 acc[4];
    #pragma unroll
    for (int fkv = 0; fkv < 4; ++fkv) acc[fkv] = f4{0.f, 0.f, 0.f, 0.f};
    #pragma unroll
    for (int fkv = 0; fkv < 4; ++fkv) {
      int r = fkv * 16 + cq;
      s16x8 a0 = *(const s16x8*)(sK_ + r * 64 + ((kb ^ (r & 7)) << 3));
      s16x8 a1 = *(const s16x8*)(sK_ + r * 64 + (((4 + kb) ^ (r & 7)) << 3));
      acc[fkv] = __builtin_amdgcn_mfma_f32_16x16x32_bf16(a0, qb0, acc[fkv], 0, 0, 0);
      acc[fkv] = __builtin_amdgcn_mfma_f32_16x16x32_bf16(a1, qb1, acc[fkv], 0, 0, 0);
    }

    // scores + online softmax (lane-local q-column; reduce over kb groups only)
    float p[4][4];
    float tm = -1e30f;
    #pragma unroll
    for (int fkv = 0; fkv < 4; ++fkv) {
      int j8 = 2 * fkv + (kb >> 1);
      u16x4 bdv = *(const u16x4*)(sB_ + qloc * 64 + ((j8 ^ sw) << 3) + (kb & 1) * 4);
      #pragma unroll
      for (int r = 0; r < 4; ++r) {
        float s = acc[fkv][r] * 0.125f + bf2f(bdv[r]);
        p[fkv][r] = s;
        tm = fmaxf(tm, s);
      }
    }
    tm = fmaxf(tm, __shfl_xor(tm, 16));
    tm = fmaxf(tm, __shfl_xor(tm, 32));
    float mn = fmaxf(m_s, tm);
    float al = __expf(m_s - mn);
    m_s = mn;
    float ps = 0.f;
    #pragma unroll
    for (int fkv = 0; fkv < 4; ++fkv)
      #pragma unroll
      for (int r = 0; r < 4; ++r) { p[fkv][r] = __expf(p[fkv][r] - mn); ps += p[fkv][r]; }
    ps += __shfl_xor(ps, 16);
    ps += __shfl_xor(ps, 32);
    l_s = l_s * al + ps;
    #pragma unroll
    for (int fd = 0; fd < 4; ++fd)
      #pragma unroll
      for (int r = 0; r < 4; ++r) O[fd][r] *= al;

    // pack P^T to bf16 pairs, exchange into PV B-fragments
    unsigned W[4][2];
    #pragma unroll
    for (int fkv = 0; fkv < 4; ++fkv) {
      W[fkv][0] = cvt_pk_bf16(p[fkv][0], p[fkv][1]);
      W[fkv][1] = cvt_pk_bf16(p[fkv][2], p[fkv][3]);
    }
    s16x8 pb[2];
    #pragma unroll
    for (int c = 0; c < 2; ++c) {
      int a00 = __builtin_amdgcn_ds_bpermute(idxA, (int)W[2 * c][0]);
      int a01 = __builtin_amdgcn_ds_bpermute(idxA, (int)W[2 * c][1]);
      int a10 = __builtin_amdgcn_ds_bpermute(idxA, (int)W[2 * c + 1][0]);
      int a11 = __builtin_amdgcn_ds_bpermute(idxA, (int)W[2 * c + 1][1]);
      int b00 = __builtin_amdgcn_ds_bpermute(idxB, (int)W[2 * c][0]);
      int b01 = __builtin_amdgcn_ds_bpermute(idxB, (int)W[2 * c][1]);
      int b10 = __builtin_amdgcn_ds_bpermute(idxB, (int)W[2 * c + 1][0]);
      int b11 = __builtin_amdgcn_ds_bpermute(idxB, (int)W[2 * c + 1][1]);
      bool hi = (kb >= 2);
      i32x4 t;
      t[0] = hi ? a10 : a00;
      t[1] = hi ? a11 : a01;
      t[2] = hi ? b10 : b00;
      t[3] = hi ? b11 : b01;
      pb[c] = *(s16x8*)&t;
    }

    // PV: O^T[d][q] += V^T @ P^T
    #pragma unroll
    for (int c = 0; c < 2; ++c)
      #pragma unroll
      for (int fd = 0; fd < 4; ++fd) {
        int rd = fd * 16 + cq;
        s16x8 vb = *(const s16x8*)(sV_ + rd * 64 + (((c * 4 + kb) ^ (rd & 7)) << 3));
        O[fd] = __builtin_amdgcn_mfma_f32_16x16x32_bf16(vb, pb[c], O[fd], 0, 0, 0);
      }
    __syncthreads();   // drains next-tile loads + read-safety for buffer reuse
  }

  // normalize + packed write: Y[(b*512+q)*512 + h*64 + d], 4 consecutive d per store
  float invl = 1.f / l_s;
  u16* yrow = Y + ((size_t)(b * 512 + q0 + qloc)) * 512 + h * 64;
  #pragma unroll
  for (int fd = 0; fd < 4; ++fd) {
    unsigned w0 = cvt_pk_bf16(O[fd][0] * invl, O[fd][1] * invl);
    unsigned w1 = cvt_pk_bf16(O[fd][2] * invl, O[fd][3] * invl);
    u32x2 st; st[0] = w0; st[1] = w1;
    *(u32x2*)(yrow + fd * 16 + kb * 4) = st;
  }
}

// ---------------- LayerNorm (D=512), fp32 in -> bf16 out ----------------
__launch_bounds__(256)
__global__ void ln_k(const float* __restrict__ x, const float* __restrict__ g,
                     const float* __restrict__ be, u16* __restrict__ out) {
  int row  = blockIdx.x * 4 + (threadIdx.x >> 6);
  int lane = threadIdx.x & 63;
  const float* xr = x + (size_t)row * 512 + lane * 8;
  f4 v0 = *(const f4*)xr;
  f4 v1 = *(const f4*)(xr + 4);
  float s = 0.f, q = 0.f;
  #pragma unroll
  for (int i = 0; i < 4; ++i) { s += v0[i] + v1[i]; q += v0[i]*v0[i] + v1[i]*v1[i]; }
  #pragma unroll
  for (int o = 32; o > 0; o >>= 1) { s += __shfl_xor(s, o); q += __shfl_xor(q, o); }
  float mu = s * (1.f / 512.f);
  float rs = rsqrtf(q * (1.f / 512.f) - mu * mu + 1e-5f);
  int c = lane * 8;
  u16x8 o;
  #pragma unroll
  for (int i = 0; i < 8; ++i) {
    float xx = (i < 4) ? v0[i] : v1[i - 4];
    o[i] = f2bf((xx - mu) * rs * g[c + i] + be[c + i]);
  }
  *(u16x8*)(out + (size_t)row * 512 + c) = o;
}

// ---------------- transpose helpers: src fp32 [R][C] -> dst bf16 [C][R] ----------------
__device__ __forceinline__ void tbody(float (*t)[65], const float* src, u16* dst,
                                      int R, int C, int bx, int by, int tid) {
  int c0 = bx * 64, r0 = by * 64;
  #pragma unroll
  for (int i = 0; i < 4; ++i) {
    int r = i * 16 + (tid >> 4);
    int c4 = (tid & 15) * 4;
    f4 v = *(const f4*)(src + (size_t)(r0 + r) * C + c0 + c4);
    t[r][c4] = v.x; t[r][c4 + 1] = v.y; t[r][c4 + 2] = v.z; t[r][c4 + 3] = v.w;
  }
  __syncthreads();
  #pragma unroll
  for (int i = 0; i < 2; ++i) {
    int id = i * 256 + tid;
    int rr = id >> 3, c8 = (id & 7) * 8;
    u16x8 o;
    #pragma unroll
    for (int j = 0; j < 8; ++j) o[j] = f2bf(t[c8 + j][rr]);
    *(u16x8*)(dst + (size_t)(c0 + rr) * R + r0 + c8) = o;
  }
}

__launch_bounds__(256)
__global__ void tsq_k(const float* aW, const float* g1W, const float* g2W, u16* wT) {
  __shared__ float t[64][65];
  int z = blockIdx.z;
  const int lut[6] = {0, 2, 1, 3, 4, 5};
  const float* src; u16* dst;
  if (z < 5)       { src = aW  + (size_t)z * 262144;        dst = wT + (size_t)z * 262144; }
  else if (z < 11) { int j = z - 5;  src = g1W + (size_t)j * 262144; dst = wT + (size_t)(5 + lut[j]) * 262144; }
  else             { int j = z - 11; src = g2W + (size_t)j * 262144; dst = wT + (size_t)(11 + lut[j]) * 262144; }
  tbody(t, src, dst, 512, 512, blockIdx.x, blockIdx.y, threadIdx.x);
}

__launch_bounds__(256)
__global__ void tgen_k(const float* src, u16* dst, int R, int C) {
  __shared__ float t[64][65];
  tbody(t, src, dst, R, C, blockIdx.x, blockIdx.y, threadIdx.x);
}

// ---------------- v transpose: kv cols 512.. -> vT[b,h][64][1024] ----------------
__launch_bounds__(256)
__global__ void vtrans_k(const u16* kv, u16* vT) {
  int jt = blockIdx.x, h = blockIdx.y, b = blockIdx.z;
  __shared__ u16 t[64][72];
  int tid = threadIdx.x;
  const u16* src = kv + ((size_t)b * 1024 + jt * 64) * 1024 + 512 + h * 64;
  #pragma unroll
  for (int i = 0; i < 2; ++i) {
    int id = i * 256 + tid;
    int r = id >> 3, c = (id & 7) * 8;
    u16x8 v = *(const u16x8*)(src + (size_t)r * 1024 + c);
    #pragma unroll
    for (int j = 0; j < 8; ++j) t[r][c + j] = v[j];
  }
  __syncthreads();
  u16* dst = vT + (size_t)(b * 8 + h) * 65536 + (size_t)jt * 64;
  #pragma unroll
  for (int i = 0; i < 2; ++i) {
    int id = i * 256 + tid;
    int d = id >> 3, c = (id & 7) * 8;
    u16x8 o;
    #pragma unroll
    for (int j = 0; j < 8; ++j) o[j] = t[c + j][d];
    *(u16x8*)(dst + (size_t)d * 1024 + c) = o;
  }
}

// ---------------- small elementwise ----------------
__launch_bounds__(256)
__global__ void conv_k(const float* in, u16* out, int n8) {
  int i = blockIdx.x * 256 + threadIdx.x;
  if (i >= n8) return;
  const float* p = in + (size_t)i * 8;
  f4 a = *(const f4*)p, b = *(const f4*)(p + 4);
  u16x8 o;
  #pragma unroll
  for (int j = 0; j < 4; ++j) { o[j] = f2bf(a[j]); o[4 + j] = f2bf(b[j]); }
  *(u16x8*)(out + (size_t)i * 8) = o;
}

__launch_bounds__(256)
__global__ void bias_k(const float* g1b, const float* g2b, float* b1, float* b2) {
  int i = blockIdx.x * 256 + threadIdx.x;
  if (i < 1024) { b1[i] = (i < 512) ? 0.f : -g1b[i - 512]; b2[i] = (i < 512) ? 0.f : -g2b[i - 512]; }
}

__launch_bounds__(256)
__global__ void rx_k(const u16* rz, const float* x, u16* rx) {
  int i = blockIdx.x * 256 + threadIdx.x;
  int m = i >> 6, d8 = (i & 63) << 3;
  u16x8 rv = *(const u16x8*)(rz + (size_t)m * 1024 + d8);
  const float* xp = x + (size_t)m * 512 + d8;
  f4 x0 = *(const f4*)xp, x1 = *(const f4*)(xp + 4);
  u16x8 o;
  #pragma unroll
  for (int j = 0; j < 4; ++j) { o[j] = f2bf(bf2f(rv[j]) * x0[j]); o[4 + j] = f2bf(bf2f(rv[4 + j]) * x1[j]); }
  *(u16x8*)(rx + (size_t)m * 512 + d8) = o;
}

__launch_bounds__(256)
__global__ void comb_k(const u16* rz, const u16* hg, const float* x, float* of, u16* ob) {
  int i = blockIdx.x * 256 + threadIdx.x;
  int m = i >> 6, d8 = (i & 63) << 3;
  u16x8 zv = *(const u16x8*)(rz + (size_t)m * 1024 + 512 + d8);
  u16x8 hv = *(const u16x8*)(hg + (size_t)m * 512 + d8);
  const float* xp = x + (size_t)m * 512 + d8;
  f4 x0 = *(const f4*)xp, x1 = *(const f4*)(xp + 4);
  f4 o0, o1; u16x8 obv;
  #pragma unroll
  for (int j = 0; j < 4; ++j) {
    float z = bf2f(zv[j]), hh = bf2f(hv[j]);
    float r = (1.f - z) * x0[j] + z * hh; o0[j] = r; obv[j] = f2bf(r);
  }
  #pragma unroll
  for (int j = 0; j < 4; ++j) {
    float z = bf2f(zv[4 + j]), hh = bf2f(hv[4 + j]);
    float r = (1.f - z) * x1[j] + z * hh; o1[j] = r; obv[4 + j] = f2bf(r);
  }
  float* op = of + (size_t)m * 512 + d8;
  *(f4*)op = o0; *(f4*)(op + 4) = o1;
  if (ob) *(u16x8*)(ob + (size_t)m * 512 + d8) = obv;
}

// ---------------- host ----------------
extern "C" void kernel_launch(void* const* d_in, const int* in_sizes, int n_in,
                              void* d_out, int out_size, void* d_ws, size_t ws_size,
                              hipStream_t stream) {
  const float* query = (const float*)d_in[0];
  const float* key   = (const float*)d_in[1];
  const float* pos   = (const float*)d_in[2];
  const float* U     = (const float*)d_in[3];
  const float* V     = (const float*)d_in[4];
  const float* attnW = (const float*)d_in[5];
  const float* ln1g  = (const float*)d_in[6];
  const float* ln1b  = (const float*)d_in[7];
  const float* ln2g  = (const float*)d_in[8];
  const float* ln2b  = (const float*)d_in[9];
  const float* g1W   = (const float*)d_in[10];
  const float* g1b   = (const float*)d_in[11];
  const float* g2W   = (const float*)d_in[12];
  const float* g2b   = (const float*)d_in[13];
  const float* fcW1  = (const float*)d_in[14];
  const float* fcb1  = (const float*)d_in[15];
  const float* fcW2  = (const float*)d_in[16];
  const float* fcb2  = (const float*)d_in[17];
  float* outp = (float*)d_out;

  char* base = (char*)d_ws;
  size_t off = 0;
  auto alloc = [&](size_t bytes) -> char* {
    char* p = base + off;
    off += (bytes + 255) & ~(size_t)255;
    return p;
  };

  u16* wT     = (u16*)alloc(17ull * 262144 * 2);
  u16* fc1T   = (u16*)alloc(2048ull * 512 * 2);
  u16* fc2T   = (u16*)alloc(2048ull * 512 * 2);
  u16* posb   = (u16*)alloc(1024ull * 512 * 2);
  u16* pbf    = (u16*)alloc(1024ull * 512 * 2);
  float* bias1 = (float*)alloc(1024 * 4);
  float* bias2 = (float*)alloc(1024 * 4);
  u16* nq     = (u16*)alloc(8192ull * 512 * 2);    // reused later as Y
  u16* nk     = (u16*)alloc(16384ull * 512 * 2);   // reused later as vT
  u16* xq     = (u16*)alloc(8192ull * 512 * 2);
  u16* qU     = (u16*)alloc(8192ull * 512 * 2);    // qU+qV reused later as out1 (fp32)
  u16* qV     = (u16*)alloc(8192ull * 512 * 2);
  u16* kv     = (u16*)alloc(16384ull * 1024 * 2);
  u16* y1     = (u16*)alloc(8192ull * 512 * 2);
  u16* ob1    = (u16*)alloc(8192ull * 512 * 2);
  u16* S      = (u16*)alloc(128ull * 524800 * 2 + 4096);  // flat-padded raw BD [B*H][512*1025]
  if (off > ws_size) return;

  // overlays
  u16* Y = nq;
  u16* vT = nk;
  float* out1f = (float*)qU;
  u16* rz1 = S;
  u16* rx1 = S + 8388608;
  u16* hg1 = rx1 + 4194304;
  u16* h2  = hg1 + 4194304;
  u16* e1  = h2 + 4194304;
  u16* y2  = e1 + 16777216;
  u16* rz2 = y2 + 4194304;
  u16* rx2 = rz2 + 8388608;
  u16* hg2 = rx2 + 4194304;

  // --- prep ---
  bias_k<<<dim3(4), dim3(256), 0, stream>>>(g1b, g2b, bias1, bias2);
  tsq_k<<<dim3(8, 8, 17), dim3(256), 0, stream>>>(attnW, g1W, g2W, wT);
  tgen_k<<<dim3(32, 8), dim3(256), 0, stream>>>(fcW1, fc1T, 512, 2048);
  tgen_k<<<dim3(8, 32), dim3(256), 0, stream>>>(fcW2, fc2T, 2048, 512);
  conv_k<<<dim3(256), dim3(256), 0, stream>>>(pos, posb, 65536);
  conv_k<<<dim3(2048), dim3(256), 0, stream>>>(query, xq, 524288);
  ln_k<<<dim3(2048), dim3(256), 0, stream>>>(query, ln1g, ln1b, nq);
  ln_k<<<dim3(4096), dim3(256), 0, stream>>>(key, ln1g, ln1b, nk);

  // --- projections ---
  { GemmP p{}; p.A = nq; p.B = wT; p.K1 = 512; p.lda = 512; p.ldb = 512; p.H = 1;
    p.C = qU; p.C2 = qV; p.ldc = 512; p.bias = U; p.bias2 = V;
    gemm_k<64,128,EPI_QUV,1><<<dim3(128,4,1), dim3(256), 0, stream>>>(p); }
  { GemmP p{}; p.A = nk; p.B = wT + 1ull*262144; p.K1 = 512; p.lda = 512; p.ldb = 512; p.H = 1;
    p.C = kv; p.ldc = 1024;
    gemm_k<64,128,EPI_BF16,1><<<dim3(256,8,1), dim3(256), 0, stream>>>(p); }
  { GemmP p{}; p.A = posb; p.B = wT + 3ull*262144; p.K1 = 512; p.lda = 512; p.ldb = 512; p.H = 1;
    p.C = pbf; p.ldc = 512;
    gemm_k<64,128,EPI_BF16,1><<<dim3(16,4,1), dim3(256), 0, stream>>>(p); }
  vtrans_k<<<dim3(16, 8, 16), dim3(256), 0, stream>>>(kv, vT);

  // --- raw BD into flat-padded buffer ---
  { GemmP p{}; p.A = qV; p.lda = 512; p.sAh = 64;
    p.B = pbf; p.ldb = 512; p.sBh = 64; p.K1 = 64; p.H = 8; p.S = S;
    gemm_k<128,128,EPI_BD,0><<<dim3(64,8,8), dim3(256), 0, stream>>>(p); }

  // --- fused attention: AC + BD + softmax + PV ---
  fattn_k<<<dim3(4, 128), dim3(512), 0, stream>>>(qU, kv, vT, S, Y);

  { GemmP p{}; p.A = Y; p.B = wT + 4ull*262144; p.K1 = 512; p.lda = 512; p.ldb = 512; p.H = 1;
    p.C = y1; p.ldc = 512;
    gemm_k<64,128,EPI_GELU,1><<<dim3(128,4,1), dim3(256), 0, stream>>>(p); }

  // --- gate 1 ---
  { GemmP p{}; p.A = y1; p.B = wT + 5ull*262144; p.K1 = 512;
    p.A2 = xq; p.B2 = wT + 7ull*262144; p.K2 = 512;
    p.lda = 512; p.ldb = 512; p.H = 1; p.C = rz1; p.ldc = 1024; p.bias = bias1;
    gemm_k<64,128,EPI_SIG,1><<<dim3(128,8,1), dim3(256), 0, stream>>>(p); }
  rx_k<<<dim3(2048), dim3(256), 0, stream>>>(rz1, query, rx1);
  { GemmP p{}; p.A = y1; p.B = wT + 9ull*262144; p.K1 = 512;
    p.A2 = rx1; p.B2 = wT + 10ull*262144; p.K2 = 512;
    p.lda = 512; p.ldb = 512; p.H = 1; p.C = hg1; p.ldc = 512;
    gemm_k<64,128,EPI_TANH,1><<<dim3(128,4,1), dim3(256), 0, stream>>>(p); }
  comb_k<<<dim3(2048), dim3(256), 0, stream>>>(rz1, hg1, query, out1f, ob1);

  // --- FFN ---
  ln_k<<<dim3(2048), dim3(256), 0, stream>>>(out1f, ln2g, ln2b, h2);
  { GemmP p{}; p.A = h2; p.B = fc1T; p.K1 = 512; p.lda = 512; p.ldb = 512; p.H = 1;
    p.C = e1; p.ldc = 2048; p.bias = fcb1;
    gemm_k<64,128,EPI_GELU,1><<<dim3(128,16,1), dim3(256), 0, stream>>>(p); }
  { GemmP p{}; p.A = e1; p.B = fc2T; p.K1 = 2048; p.lda = 2048; p.ldb = 2048; p.H = 1;
    p.C = y2; p.ldc = 512; p.bias = fcb2;
    gemm_k<64,128,EPI_GELU,1><<<dim3(128,4,1), dim3(256), 0, stream>>>(p); }

  // --- gate 2 ---
  { GemmP p{}; p.A = y2; p.B = wT + 11ull*262144; p.K1 = 512;
    p.A2 = ob1; p.B2 = wT + 13ull*262144; p.K2 = 512;
    p.lda = 512; p.ldb = 512; p.H = 1; p.C = rz2; p.ldc = 1024; p.bias = bias2;
    gemm_k<64,128,EPI_SIG,1><<<dim3(128,8,1), dim3(256), 0, stream>>>(p); }
  rx_k<<<dim3(2048), dim3(256), 0, stream>>>(rz2, out1f, rx2);
  { GemmP p{}; p.A = y2; p.B = wT + 15ull*262144; p.K1 = 512;
    p.A2 = rx2; p.B2 = wT + 16ull*262144; p.K2 = 512;
    p.lda = 512; p.ldb = 512; p.H = 1; p.C = hg2; p.ldc = 512;
    gemm_k<64,128,EPI_TANH,1><<<dim3(128,4,1), dim3(256), 0, stream>>>(p); }
  comb_k<<<dim3(2048), dim3(256), 0, stream>>>(rz2, hg2, out1f, outp, (u16*)nullptr);
}